// Round 20
// baseline (2588.551 us; speedup 1.0000x reference)
//
#include <hip/hip_runtime.h>
#include <math.h>

#define BB 8
#define LL 196
#define DD 384
#define NDEPTH 24
#define NST 16
#define RRANK 24
#define HHID 1024
#define MROWS (BB*LL)   /* 1568 */
#define NCH 28
#define CHL 7

typedef float f32x4 __attribute__((ext_vector_type(4)));
typedef short s16x8 __attribute__((ext_vector_type(8)));
typedef short s16x4 __attribute__((ext_vector_type(4)));
typedef __bf16 b16x8 __attribute__((ext_vector_type(8)));
typedef unsigned short u16;
typedef unsigned int u32;

#if defined(__has_builtin)
#  if __has_builtin(__builtin_amdgcn_global_load_lds)
#    define HAS_GLL 1
#  endif
#endif
#ifndef HAS_GLL
#  define HAS_GLL 0
#endif

__device__ __forceinline__ float sigmoidf_(float x){ return 1.f/(1.f+__expf(-x)); }

__device__ __forceinline__ u16 f2bf(float f){
    u32 u = __builtin_bit_cast(u32, f);
    u32 r = (u + 0x7fffu + ((u >> 16) & 1u)) >> 16;   // RNE
    return (u16)r;
}
__device__ __forceinline__ float bf2f(u16 v){
    u32 u = ((u32)v) << 16;
    return __builtin_bit_cast(float, u);
}

// async global->LDS, 16B per lane; LDS dest is wave-uniform base + lane*16
__device__ __forceinline__ void gll16(const u16* g, void* lds){
#if HAS_GLL
    __builtin_amdgcn_global_load_lds(
        (const __attribute__((address_space(1))) unsigned int*)g,
        (__attribute__((address_space(3))) unsigned int*)lds, 16, 0, 0);
#endif
}

// counted-vmcnt barrier (m218 pattern)
template<int N> __device__ __forceinline__ void waitbar(){
    if constexpr (N==0) asm volatile("s_waitcnt vmcnt(0) lgkmcnt(0)\ns_barrier" ::: "memory");
    else if constexpr (N==4) asm volatile("s_waitcnt vmcnt(4) lgkmcnt(0)\ns_barrier" ::: "memory");
    else if constexpr (N==8) asm volatile("s_waitcnt vmcnt(8) lgkmcnt(0)\ns_barrier" ::: "memory");
    else asm volatile("s_waitcnt vmcnt(0) lgkmcnt(0)\ns_barrier" ::: "memory");
    __builtin_amdgcn_sched_barrier(0);
}
// release barrier: drain THIS wave's LDS reads, keep vmcnt prefetch in flight.
__device__ __forceinline__ void bar_release(){
    asm volatile("s_waitcnt lgkmcnt(0)\ns_barrier" ::: "memory");
    __builtin_amdgcn_sched_barrier(0);
}

// ---- MFMA wrapper: SFINAE hedge over builtin operand type ----
template<typename V>
__device__ __forceinline__ auto mfma_try(V a, V b, f32x4 c, int)
    -> decltype(__builtin_amdgcn_mfma_f32_16x16x32_bf16(a, b, c, 0, 0, 0))
{ return __builtin_amdgcn_mfma_f32_16x16x32_bf16(a, b, c, 0, 0, 0); }

template<typename V>
__device__ __forceinline__ f32x4 mfma_try(V a, V b, f32x4 c, long)
{
    return __builtin_amdgcn_mfma_f32_16x16x32_bf16(
        __builtin_bit_cast(b16x8, a), __builtin_bit_cast(b16x8, b), c, 0, 0, 0);
}
__device__ __forceinline__ f32x4 mfma_bf16(s16x8 a, s16x8 b, f32x4 c){ return mfma_try(a, b, c, 0); }

// ---------------- LayerNorm f32 out (final only) ----------------
__global__ __launch_bounds__(64) void ln_k(const float* __restrict__ X,
    const float* __restrict__ w, const float* __restrict__ b, float* __restrict__ Y)
{
    int row = blockIdx.x;
    int lane = threadIdx.x;
    const float* x = X + (size_t)row*DD;
    float v[6]; float s=0.f, s2=0.f;
    #pragma unroll
    for (int j=0;j<6;j++){ float t = x[lane + j*64]; v[j]=t; s+=t; s2+=t*t; }
    #pragma unroll
    for (int o=32;o>=1;o>>=1){ s += __shfl_xor(s,o); s2 += __shfl_xor(s2,o); }
    float m = s*(1.f/DD);
    float var = s2*(1.f/DD) - m*m;
    float rstd = rsqrtf(var + 1e-5f);
    #pragma unroll
    for (int j=0;j<6;j++){
        int c = lane + j*64;
        Y[(size_t)row*DD + c] = (v[j]-m)*rstd*w[c] + b[c];
    }
}

// ---------------- Patch gather -> bf16 (B*L, 768) ----------------
__global__ void gather_k(const float* __restrict__ x, u16* __restrict__ P)
{
    int idx = blockIdx.x*blockDim.x + threadIdx.x;
    if (idx >= MROWS*768) return;
    int k = idx % 768;
    int bl = idx / 768;
    int l = bl % LL;
    int b = bl / LL;
    int c = k >> 8;
    int rem = k & 255;
    int dy = rem >> 4, dx = rem & 15;
    int py = l / 14, px = l % 14;
    P[idx] = f2bf(x[(((size_t)b*3 + c)*224 + (py*16+dy))*224 + (px*16+dx)]);
}

// ---------------- MFMA bf16 GEMM (counted-vmcnt 2-buffer pipeline; early C-read) ----------------
__device__ __forceinline__ int swz(int row, int chunk){
    return (row << 7) + ((chunk ^ (row & 7)) << 4);
}

template<int EPI, bool WB, int CFG, int PRO, int K>
__global__ __launch_bounds__(256) void mgemm_k(
    const u16* __restrict__ A, const float* __restrict__ Af,
    const float* __restrict__ lnw, const float* __restrict__ lnb,
    const void* __restrict__ W1v, const void* __restrict__ W2v,
    const float* __restrict__ bias1, const float* __restrict__ bias2,
    float* __restrict__ Cf, u16* __restrict__ Cb,
    int M, int N)
{
    constexpr int  BM   = (CFG==1)?32:16;
    constexpr int  FM   = (CFG==2)?1:2;
    constexpr int  FN   = 2;
    constexpr int  NAR  = (BM+31)/32;
    constexpr bool DUAL = (EPI==4);
    constexpr bool RES  = (EPI==2 || EPI==3);
    constexpr int  ABY  = BM*128;
    constexpr int  BBY  = 128*128;
    constexpr bool ASY  = WB && (HAS_GLL==1);
    constexpr int  NKT  = K >> 6;
    constexpr int  NLW  = DUAL ? 8 : 4;
    __shared__ __attribute__((aligned(16))) char sm[2*ABY + 2*BBY + (DUAL ? 2*BBY : 0)];
    char* A0 = sm;          char* A1 = sm + ABY;
    char* B0 = sm + 2*ABY;  char* B1 = B0 + BBY;
    char* C0 = B1 + BBY;    char* C1 = C0 + BBY;

    const int tid = threadIdx.x;
    const int row0 = blockIdx.y * BM;
    const int col0 = blockIdx.x << 7;
    const int w = tid >> 6, lane = tid & 63;
    const int wn  = w;
    const int lr = lane & 15, lk = lane >> 4;
    const int ar0 = tid >> 3, ac8 = tid & 7;
    const bool apart = (CFG != 2) || (tid < 128);

    const u16*   W1b = (const u16*)W1v;
    const u16*   W2b = (const u16*)W2v;
    const float* W1f = (const float*)W1v;
    const float* W2f = (const float*)W2v;

    f32x4 acc [FM][FN] = {};
    f32x4 acc2[FM][FN] = {};

    float cres[FM][FN][4];
    if (RES){
        #pragma unroll
        for (int n=0;n<FN;n++){
            int gc = col0 + wn*32 + n*16 + lr;
            #pragma unroll
            for (int m=0;m<FM;m++){
                #pragma unroll
                for (int r=0;r<4;r++){
                    int gr = row0 + m*16 + lk*4 + r;
                    cres[m][n][r] = (gc < N && gr < M) ? Cf[(size_t)gr*N + gc] : 0.f;
                }
            }
        }
    }

    s16x8 aval[NAR];
    s16x8 bval[4], b2val[4];
    float4 bvf[8], b2vf[8];
    s16x8 lnr[(PRO==1)?NKT:1];

    if (PRO == 1 && apart){
        const float* xrow = Af + (size_t)(row0 + ar0)*DD;
        float4 va[6], vb[6];
        float s = 0.f, s2 = 0.f;
        #pragma unroll
        for (int j=0;j<6;j++){
            va[j] = *(const float4*)(xrow + j*64 + ac8*8);
            vb[j] = *(const float4*)(xrow + j*64 + ac8*8 + 4);
            s  += va[j].x+va[j].y+va[j].z+va[j].w + vb[j].x+vb[j].y+vb[j].z+vb[j].w;
            s2 += va[j].x*va[j].x+va[j].y*va[j].y+va[j].z*va[j].z+va[j].w*va[j].w
                + vb[j].x*vb[j].x+vb[j].y*vb[j].y+vb[j].z*vb[j].z+vb[j].w*vb[j].w;
        }
        #pragma unroll
        for (int o=1;o<8;o<<=1){ s += __shfl_xor(s,o); s2 += __shfl_xor(s2,o); }
        float m = s*(1.f/DD);
        float rstd = rsqrtf(s2*(1.f/DD) - m*m + 1e-5f);
        #pragma unroll
        for (int j=0;j<6;j++){
            int c0 = j*64 + ac8*8;
            float4 w0 = *(const float4*)(lnw + c0);
            float4 w1 = *(const float4*)(lnw + c0 + 4);
            float4 b0 = *(const float4*)(lnb + c0);
            float4 b1 = *(const float4*)(lnb + c0 + 4);
            s16x8 ov;
            ov[0]=(short)f2bf((va[j].x-m)*rstd*w0.x+b0.x);
            ov[1]=(short)f2bf((va[j].y-m)*rstd*w0.y+b0.y);
            ov[2]=(short)f2bf((va[j].z-m)*rstd*w0.z+b0.z);
            ov[3]=(short)f2bf((va[j].w-m)*rstd*w0.w+b0.w);
            ov[4]=(short)f2bf((vb[j].x-m)*rstd*w1.x+b1.x);
            ov[5]=(short)f2bf((vb[j].y-m)*rstd*w1.y+b1.y);
            ov[6]=(short)f2bf((vb[j].z-m)*rstd*w1.z+b1.z);
            ov[7]=(short)f2bf((vb[j].w-m)*rstd*w1.w+b1.w);
            if (j < NKT) lnr[j] = ov;
        }
    }

    auto stageAsync = [&](int kt, char* bA, char* bB, char* bC){
        const int lhi = lane >> 3, llo = lane & 7;
        const int colel = (kt << 6) + ((llo ^ lhi) << 3);
        if (PRO == 0){
            constexpr int ACH = BM/8;
            #pragma unroll
            for (int ci = w; ci < ACH; ci += 4){
                int gr = row0 + ci*8 + lhi;
                gll16(A + (size_t)gr*K + colel, bA + ci*1024);
            }
        }
        #pragma unroll
        for (int i=0;i<4;i++){
            int ci = w*4 + i;
            int gb = col0 + ci*8 + lhi;
            gll16(W1b + (size_t)gb*K + colel, bB + ci*1024);
        }
        if (DUAL){
            #pragma unroll
            for (int i=0;i<4;i++){
                int ci = w*4 + i;
                int gb = col0 + ci*8 + lhi;
                gll16(W2b + (size_t)gb*K + colel, bC + ci*1024);
            }
        }
    };

    auto loadT = [&](int kt){
        const int kb = kt << 6;
        if (PRO == 0 && apart){
            #pragma unroll
            for (int i=0;i<NAR;i++){
                int gr = row0 + i*32 + ar0;
                if (gr < M) aval[i] = *(const s16x8*)(A + (size_t)gr*K + kb + ac8*8);
                else        aval[i] = s16x8{0,0,0,0,0,0,0,0};
            }
        }
        if (WB){
            #pragma unroll
            for (int i=0;i<4;i++){
                int gb = col0 + i*32 + ar0;
                if (gb < N) bval[i] = *(const s16x8*)(W1b + (size_t)gb*K + kb + ac8*8);
                else        bval[i] = s16x8{0,0,0,0,0,0,0,0};
            }
            if (DUAL){
                #pragma unroll
                for (int i=0;i<4;i++){
                    int gb = col0 + i*32 + ar0;
                    if (gb < N) b2val[i] = *(const s16x8*)(W2b + (size_t)gb*K + kb + ac8*8);
                    else        b2val[i] = s16x8{0,0,0,0,0,0,0,0};
                }
            }
        } else {
            #pragma unroll
            for (int i=0;i<8;i++){
                int ss = i*256 + tid;
                int r = ss >> 4, q = ss & 15;
                int gb = col0 + r;
                if (gb < N) bvf[i] = *(const float4*)(W1f + (size_t)gb*K + kb + q*4);
                else        bvf[i] = float4{0,0,0,0};
            }
            if (DUAL){
                #pragma unroll
                for (int i=0;i<8;i++){
                    int ss = i*256 + tid;
                    int r = ss >> 4, q = ss & 15;
                    int gb = col0 + r;
                    if (gb < N) b2vf[i] = *(const float4*)(W2f + (size_t)gb*K + kb + q*4);
                    else        b2vf[i] = float4{0,0,0,0};
                }
            }
        }
    };
    auto writeT = [&](char* bA, char* bB, char* bC){
        if (PRO == 0 && apart){
            #pragma unroll
            for (int i=0;i<NAR;i++)
                *(s16x8*)(bA + swz(i*32 + ar0, ac8)) = aval[i];
        }
        if (WB){
            #pragma unroll
            for (int i=0;i<4;i++)
                *(s16x8*)(bB + swz(i*32 + ar0, ac8)) = bval[i];
            if (DUAL){
                #pragma unroll
                for (int i=0;i<4;i++)
                    *(s16x8*)(bC + swz(i*32 + ar0, ac8)) = b2val[i];
            }
        } else {
            #pragma unroll
            for (int i=0;i<8;i++){
                int ss = i*256 + tid;
                int r = ss >> 4, q = ss & 15;
                float4 v = bvf[i];
                s16x4 cv = { (short)f2bf(v.x), (short)f2bf(v.y), (short)f2bf(v.z), (short)f2bf(v.w) };
                int off = (r << 7) + (((q >> 1) ^ (r & 7)) << 4) + ((q & 1) << 3);
                *(s16x4*)(bB + off) = cv;
            }
            if (DUAL){
                #pragma unroll
                for (int i=0;i<8;i++){
                    int ss = i*256 + tid;
                    int r = ss >> 4, q = ss & 15;
                    float4 v = b2vf[i];
                    s16x4 cv = { (short)f2bf(v.x), (short)f2bf(v.y), (short)f2bf(v.z), (short)f2bf(v.w) };
                    int off = (r << 7) + (((q >> 1) ^ (r & 7)) << 4) + ((q & 1) << 3);
                    *(s16x4*)(bC + off) = cv;
                }
            }
        }
    };

    auto compute = [&](char* cA, char* cB, char* cC){
        #pragma unroll
        for (int ks=0; ks<2; ks++){
            s16x8 af[FM], bfr[FN];
            #pragma unroll
            for (int m=0;m<FM;m++)
                af[m] = *(const s16x8*)(cA + swz(m*16 + lr, ks*4 + lk));
            #pragma unroll
            for (int n=0;n<FN;n++)
                bfr[n] = *(const s16x8*)(cB + swz(wn*32 + n*16 + lr, ks*4 + lk));
            #pragma unroll
            for (int m=0;m<FM;m++)
                #pragma unroll
                for (int n=0;n<FN;n++)
                    acc[m][n] = mfma_bf16(af[m], bfr[n], acc[m][n]);
            if (DUAL){
                s16x8 b2r[FN];
                #pragma unroll
                for (int n=0;n<FN;n++)
                    b2r[n] = *(const s16x8*)(cC + swz(wn*32 + n*16 + lr, ks*4 + lk));
                #pragma unroll
                for (int m=0;m<FM;m++)
                    #pragma unroll
                    for (int n=0;n<FN;n++)
                        acc2[m][n] = mfma_bf16(af[m], b2r[n], acc2[m][n]);
            }
        }
    };

    if (ASY){
        stageAsync(0, A0, B0, C0);
        if (NKT > 1) stageAsync(1, A1, B1, C1);
        if (PRO == 1 && apart){
            *(s16x8*)(A0 + swz(ar0, ac8)) = lnr[0];
            if (NKT > 1) *(s16x8*)(A1 + swz(ar0, ac8)) = lnr[(1 < NKT) ? 1 : 0];
        }
        if (NKT > 1) waitbar<NLW>(); else waitbar<0>();
        #pragma unroll
        for (int kt=0; kt<NKT; kt++){
            if (kt & 1) compute(A1, B1, C1);
            else        compute(A0, B0, C0);
            if (kt+1 < NKT){
                bar_release();
                if (kt+2 < NKT){
                    char* rA = (kt&1)?A1:A0; char* rB = (kt&1)?B1:B0; char* rC = (kt&1)?C1:C0;
                    stageAsync(kt+2, rA, rB, rC);
                    if (PRO == 1 && apart)
                        *(s16x8*)(rA + swz(ar0, ac8)) = lnr[(kt+2 < NKT) ? (kt+2) : 0];
                    waitbar<NLW>();
                } else {
                    waitbar<0>();
                }
            }
        }
    } else {
        loadT(0); writeT(A0, B0, C0);
        if (PRO == 1 && apart) *(s16x8*)(A0 + swz(ar0, ac8)) = lnr[0];
        __syncthreads();
        #pragma unroll
        for (int kt=0; kt<NKT; kt++){
            const bool more = (kt+1 < NKT);
            char* nA = (kt&1)?A0:A1; char* nB = (kt&1)?B0:B1; char* nC = (kt&1)?C0:C1;
            if (more){
                loadT(kt+1);
                if (PRO == 1 && apart) *(s16x8*)(nA + swz(ar0, ac8)) = lnr[(kt+1 < NKT) ? (kt+1) : 0];
            }
            if (kt & 1) compute(A1, B1, C1);
            else        compute(A0, B0, C0);
            if (more) writeT(nA, nB, nC);
            __syncthreads();
        }
    }

    #pragma unroll
    for (int n=0;n<FN;n++){
        int gc = col0 + wn*32 + n*16 + lr;
        if (gc >= N) continue;
        float b1 = 0.f, b2 = 0.f;
        if (EPI==1||EPI==3||EPI==4) b1 = bias1[gc];
        if (EPI==4) b2 = bias2[gc];
        #pragma unroll
        for (int m=0;m<FM;m++){
            #pragma unroll
            for (int r=0;r<4;r++){
                int gr = row0 + m*16 + lk*4 + r;
                if (gr >= M) continue;
                float v = acc[m][n][r];
                if (EPI==1||EPI==3) v += b1;
                if (RES) v += cres[m][n][r];
                if (EPI==4){
                    float v1 = v + b1;
                    float v2 = acc2[m][n][r] + b2;
                    Cb[(size_t)gr*N + gc] = f2bf(v1 * sigmoidf_(v1) * v2);
                } else if (EPI==6){
                    Cb[(size_t)gr*N + gc] = f2bf(v);
                } else {
                    Cf[(size_t)gr*N + gc] = v;
                }
            }
        }
    }
}

// ---------------- fp32 -> bf16 weight conversion ----------------
__global__ void cvtw_k(const float* __restrict__ s, u16* __restrict__ d, int n)
{
    int i = blockIdx.x*blockDim.x + threadIdx.x;
    int idx = i*4;
    if (idx + 4 <= n){
        float4 v = *(const float4*)(s + idx);
        s16x4 cv = { (short)f2bf(v.x), (short)f2bf(v.y), (short)f2bf(v.z), (short)f2bf(v.w) };
        *(s16x4*)(d + idx) = cv;
    } else {
        for (int j=idx;j<n;j++) d[j] = f2bf(s[j]);
    }
}

// ---------------- Scan phase A (x_proj fused): conv+SiLU -> xa in LDS ->
//  in-block f32 GEMV for dbc -> dt_proj + local chunk scan; stores {dtv,xv}, P, S ----------------
__global__ __launch_bounds__(384) void scanA_k(
    const float* __restrict__ Wx, const u16* __restrict__ xzb,
    const float* __restrict__ cw, const float* __restrict__ cb,
    const float* __restrict__ dtw, const float* __restrict__ dtb,
    const float* __restrict__ a_log,
    float* __restrict__ Pout, float* __restrict__ Sout,
    float2* __restrict__ dtxv, float* __restrict__ dbc)
{
    __shared__ float xaS[CHL][DD+4];
    __shared__ float Ds[CHL][56];
    int b = blockIdx.x / NCH;
    int c = blockIdx.x % NCH;
    int d = threadIdx.x;

    float cwr[4];
    #pragma unroll
    for (int k=0;k<4;k++) cwr[k] = cw[d*4+k];
    float cbv = cb[d];
    int l0 = c*CHL;
    float p3=0.f, p2=0.f, p1=0.f;
    if (l0 >= 3) p3 = bf2f(xzb[(size_t)(b*LL+l0-3)*768 + d]);
    if (l0 >= 2) p2 = bf2f(xzb[(size_t)(b*LL+l0-2)*768 + d]);
    if (l0 >= 1) p1 = bf2f(xzb[(size_t)(b*LL+l0-1)*768 + d]);
    float xv[CHL];
    #pragma unroll
    for (int j=0;j<CHL;j++){
        int row = b*LL + l0 + j;
        float cur = bf2f(xzb[(size_t)row*768 + d]);
        float a = cbv;
        a = fmaf(p3, cwr[0], a); a = fmaf(p2, cwr[1], a);
        a = fmaf(p1, cwr[2], a); a = fmaf(cur, cwr[3], a);
        p3 = p2; p2 = p1; p1 = cur;
        xv[j] = a * sigmoidf_(a);
        xaS[j][d] = xv[j];
    }
    __syncthreads();

    for (int t = d; t < CHL*56; t += 384){
        int q = t / CHL, j = t - q*CHL;
        const float* Wr = Wx + (size_t)q*DD;
        float accd = 0.f;
        #pragma unroll 8
        for (int dd=0; dd<DD; dd+=4){
            float4 wv = *(const float4*)(Wr + dd);
            accd = fmaf(xaS[j][dd],   wv.x, accd);
            accd = fmaf(xaS[j][dd+1], wv.y, accd);
            accd = fmaf(xaS[j][dd+2], wv.z, accd);
            accd = fmaf(xaS[j][dd+3], wv.w, accd);
        }
        Ds[j][q] = accd;
        dbc[(size_t)(b*LL + l0 + j)*56 + q] = accd;
    }
    __syncthreads();

    float dtwr[RRANK];
    #pragma unroll
    for (int r=0;r<RRANK;r++) dtwr[r] = dtw[d*RRANK + r];
    float dtbv = dtb[d];
    float Aa[NST];
    #pragma unroll
    for (int n=0;n<NST;n++) Aa[n] = -__expf(a_log[d*NST+n]);
    float hst[NST], P[NST];
    #pragma unroll
    for (int n=0;n<NST;n++){ hst[n]=0.f; P[n]=1.f; }
    #pragma unroll
    for (int j=0;j<CHL;j++){
        int row = b*LL + l0 + j;
        float t = dtbv;
        #pragma unroll
        for (int r=0;r<RRANK;r++) t = fmaf(dtwr[r], Ds[j][r], t);
        float dtv = (t > 20.f) ? t : log1pf(__expf(t));
        dtxv[(size_t)row*DD + d] = float2{dtv, xv[j]};
        float du = dtv*xv[j];
        #pragma unroll
        for (int n=0;n<NST;n++){
            float e = __expf(dtv*Aa[n]);
            hst[n] = fmaf(hst[n], e, du*Ds[j][24+n]);
            P[n] *= e;
        }
    }
    size_t base = ((size_t)(b*NCH + c)*DD + d)*NST;
    #pragma unroll
    for (int n=0;n<NST;n++){ Pout[base+n]=P[n]; Sout[base+n]=hst[n]; }
}

// ---------------- Scan phase C (out_proj FUSED): prefix + replay + gate -> yg in LDS ->
//  in-block f32 GEMV vs out_w -> residual update of h ----------------
__global__ __launch_bounds__(384) void scanC_k(
    const float* __restrict__ dbc, const float2* __restrict__ dtxv,
    const u16* __restrict__ xzb, const float* __restrict__ a_log,
    const float* __restrict__ Pin, const float* __restrict__ Sin,
    const float* __restrict__ dskip, const float* __restrict__ Wo,
    float* __restrict__ h)
{
    __shared__ float ygS[CHL][DD+4];
    __shared__ float Ds[CHL][56];
    int b = blockIdx.x / NCH;
    int c = blockIdx.x % NCH;
    int d = threadIdx.x;
    for (int t = threadIdx.x; t < CHL*56; t += 384){
        int j = t/56, q = t%56;
        Ds[j][q] = dbc[(size_t)(b*LL + c*CHL + j)*56 + q];
    }
    __syncthreads();
    float hst[NST];
    #pragma unroll
    for (int n=0;n<NST;n++) hst[n]=0.f;
    for (int cc=0; cc<c; cc++){
        size_t base = ((size_t)(b*NCH + cc)*DD + d)*NST;
        #pragma unroll
        for (int n=0;n<NST;n++)
            hst[n] = fmaf(Pin[base+n], hst[n], Sin[base+n]);
    }
    float Aa[NST];
    #pragma unroll
    for (int n=0;n<NST;n++) Aa[n] = -__expf(a_log[d*NST+n]);
    float dsk = dskip[d];
    int l0 = c*CHL;
    #pragma unroll
    for (int j=0;j<CHL;j++){
        int row = b*LL + l0 + j;
        float2 dx = dtxv[(size_t)row*DD + d];
        float dtv = dx.x, xv = dx.y;
        float du = dtv*xv;
        float y = 0.f;
        #pragma unroll
        for (int n=0;n<NST;n++){
            float e = __expf(dtv*Aa[n]);
            hst[n] = fmaf(hst[n], e, du*Ds[j][24+n]);
            y = fmaf(hst[n], Ds[j][40+n], y);
        }
        float zv = bf2f(xzb[(size_t)row*768 + 384 + d]);
        float g = zv * sigmoidf_(zv);
        ygS[j][d] = (y + dsk*xv)*g;
    }
    __syncthreads();

    // ---- out_proj GEMV: thread e computes o[j] = sum_d ygS[j][d]*Wo[e][d]; h += o ----
    const float* Wr = Wo + (size_t)d*DD;
    float o[CHL];
    #pragma unroll
    for (int j=0;j<CHL;j++) o[j] = 0.f;
    #pragma unroll 4
    for (int dd=0; dd<DD; dd+=4){
        float4 wv = *(const float4*)(Wr + dd);
        #pragma unroll
        for (int j=0;j<CHL;j++){
            o[j] = fmaf(ygS[j][dd],   wv.x, o[j]);
            o[j] = fmaf(ygS[j][dd+1], wv.y, o[j]);
            o[j] = fmaf(ygS[j][dd+2], wv.z, o[j]);
            o[j] = fmaf(ygS[j][dd+3], wv.w, o[j]);
        }
    }
    #pragma unroll
    for (int j=0;j<CHL;j++){
        size_t idx = (size_t)(b*LL + l0 + j)*DD + d;
        h[idx] += o[j];
    }
}

// ---------------- host-side MFMA launcher (WB gating) ----------------
template<int EPI, int CFG, int PRO, int K>
static void mg(bool wb, dim3 g, hipStream_t s,
               const void* A, const float* Af, const float* lnw, const float* lnb,
               const void* Wb, const void* Wf, const void* W2b, const void* W2f,
               const float* b1, const float* b2, float* Cf, u16* Cb,
               int M, int N)
{
    if (wb) mgemm_k<EPI,true ,CFG,PRO,K><<<g,256,0,s>>>((const u16*)A, Af, lnw, lnb, Wb, W2b, b1, b2, Cf, Cb, M, N);
    else    mgemm_k<EPI,false,CFG,PRO,K><<<g,256,0,s>>>((const u16*)A, Af, lnw, lnb, Wf, W2f, b1, b2, Cf, Cb, M, N);
}

extern "C" void kernel_launch(void* const* d_in, const int* in_sizes, int n_in,
                              void* d_out, int out_size, void* d_ws, size_t ws_size,
                              hipStream_t stream)
{
    const float* x         = (const float*)d_in[0];
    const float* patch_w   = (const float*)d_in[1];
    const float* patch_b   = (const float*)d_in[2];
    const float* norm1_w   = (const float*)d_in[3];
    const float* norm1_b   = (const float*)d_in[4];
    const float* in_proj_w = (const float*)d_in[5];
    const float* conv_w    = (const float*)d_in[6];
    const float* conv_b    = (const float*)d_in[7];
    const float* x_proj_w  = (const float*)d_in[8];
    const float* dt_w      = (const float*)d_in[9];
    const float* dt_b      = (const float*)d_in[10];
    const float* A_log     = (const float*)d_in[11];
    const float* D_skip    = (const float*)d_in[12];
    const float* out_w     = (const float*)d_in[13];
    const float* norm2_w   = (const float*)d_in[14];
    const float* norm2_b   = (const float*)d_in[15];
    const float* w1_w      = (const float*)d_in[16];
    const float* w1_b      = (const float*)d_in[17];
    const float* w2_w      = (const float*)d_in[18];
    const float* w2_b      = (const float*)d_in[19];
    const float* w3_w      = (const float*)d_in[20];
    const float* w3_b      = (const float*)d_in[21];
    const float* normf_w   = (const float*)d_in[22];
    const float* normf_b   = (const float*)d_in[23];

    char* wsb = (char*)d_ws;
    size_t o = 0;
    auto take = [&](size_t bytes) -> char* {
        char* p = wsb + o;
        o += (bytes + 255) & ~(size_t)255;
        return p;
    };

    float* h    = (float*)take((size_t)602112*4);
    float* dbc  = (float*)take((size_t)87808*4);
    float* Pb   = (float*)take((size_t)BB*NCH*DD*NST*4);
    float* Sb   = (float*)take((size_t)BB*NCH*DD*NST*4);
    float2* dtxv= (float2*)take((size_t)MROWS*DD*8);
    u16*  xzb   = (u16*)take((size_t)1204224*2);
    u16*  hid   = (u16*)take((size_t)1605632*2);
    u16*  patches = hid;   // alias: consumed before hid is produced

    const size_t NPW = 294912, NIN = 7077888,
                 NW1 = 9437184, NW2 = 9437184, NW3 = 9437184;
    u16* wcP = (u16*)take(NPW*2);
    u16* wcI = (u16*)take(NIN*2);
    u16* wc1 = (u16*)take(NW1*2);
    u16* wc2 = (u16*)take(NW2*2);
    u16* wc3 = (u16*)take(NW3*2);
    bool wb = (ws_size >= o);

    if (wb){
        cvtw_k<<<(int)((NPW/4+255)/256), 256, 0, stream>>>(patch_w, wcP, (int)NPW);
        cvtw_k<<<(int)((NIN/4+255)/256), 256, 0, stream>>>(in_proj_w, wcI, (int)NIN);
        cvtw_k<<<(int)((NW1/4+255)/256), 256, 0, stream>>>(w1_w, wc1, (int)NW1);
        cvtw_k<<<(int)((NW2/4+255)/256), 256, 0, stream>>>(w2_w, wc2, (int)NW2);
        cvtw_k<<<(int)((NW3/4+255)/256), 256, 0, stream>>>(w3_w, wc3, (int)NW3);
    }

    const int GY32 = MROWS/32;   // 49
    const int GY16 = MROWS/16;   // 98

    // Patch embedding
    gather_k<<<(MROWS*768+255)/256, 256, 0, stream>>>(x, patches);
    mg<1,2,0,768>(wb, dim3(3,GY16), stream, patches, nullptr, nullptr, nullptr,
              wcP, patch_w, nullptr, nullptr, patch_b, nullptr, h, nullptr, MROWS, DD);

    for (int i=0;i<NDEPTH;i++){
        // in_proj with register-LN prologue -> xzb bf16 (CFG1, 294 blocks)
        mg<6,1,1,384>(wb, dim3(6,GY32), stream, nullptr, h, norm1_w + i*DD, norm1_b + i*DD,
                  wcI + (size_t)i*768*DD, in_proj_w + (size_t)i*768*DD, nullptr, nullptr,
                  nullptr, nullptr, nullptr, xzb, MROWS, 768);
        // fused conv+SiLU + x_proj GEMV + dt + local scan
        scanA_k<<<BB*NCH, 384, 0, stream>>>(x_proj_w + (size_t)i*56*DD, xzb,
                                            conv_w + i*DD*4, conv_b + i*DD,
                                            dt_w + (size_t)i*DD*RRANK, dt_b + i*DD,
                                            A_log + (size_t)i*DD*NST, Pb, Sb, dtxv, dbc);
        // fused prefix+replay+gate + out_proj GEMV + residual
        scanC_k<<<BB*NCH, 384, 0, stream>>>(dbc, dtxv, xzb, A_log + (size_t)i*DD*NST,
                                            Pb, Sb, D_skip + i*DD,
                                            out_w + (size_t)i*DD*DD, h);
        // MLP dual with register-LN prologue -> hid bf16 (CFG1, 392 blocks)
        mg<4,1,1,384>(wb, dim3(8,GY32), stream, nullptr, h, norm2_w + i*DD, norm2_b + i*DD,
                  wc1 + (size_t)i*HHID*DD, w1_w + (size_t)i*HHID*DD,
                  wc2 + (size_t)i*HHID*DD, w2_w + (size_t)i*HHID*DD,
                  w1_b + i*HHID, w2_b + i*HHID, nullptr, hid, MROWS, HHID);
        mg<3,2,0,1024>(wb, dim3(3,GY16), stream, hid, nullptr, nullptr, nullptr,
                  wc3 + (size_t)i*DD*HHID, w3_w + (size_t)i*DD*HHID, nullptr, nullptr,
                  w3_b + i*DD, nullptr, h, nullptr, MROWS, DD);
    }

    ln_k<<<MROWS, 64, 0, stream>>>(h, normf_w, normf_b, (float*)d_out);
}

// Round 21
// 2427.619 us; speedup vs baseline: 1.0663x; 1.0663x over previous
//
#include <hip/hip_runtime.h>
#include <math.h>

#define BB 8
#define LL 196
#define DD 384
#define NDEPTH 24
#define NST 16
#define RRANK 24
#define HHID 1024
#define MROWS (BB*LL)   /* 1568 */
#define NCH 28
#define CHL 7

typedef float f32x4 __attribute__((ext_vector_type(4)));
typedef short s16x8 __attribute__((ext_vector_type(8)));
typedef short s16x4 __attribute__((ext_vector_type(4)));
typedef __bf16 b16x8 __attribute__((ext_vector_type(8)));
typedef unsigned short u16;
typedef unsigned int u32;

#if defined(__has_builtin)
#  if __has_builtin(__builtin_amdgcn_global_load_lds)
#    define HAS_GLL 1
#  endif
#endif
#ifndef HAS_GLL
#  define HAS_GLL 0
#endif

__device__ __forceinline__ float sigmoidf_(float x){ return 1.f/(1.f+__expf(-x)); }

__device__ __forceinline__ u16 f2bf(float f){
    u32 u = __builtin_bit_cast(u32, f);
    u32 r = (u + 0x7fffu + ((u >> 16) & 1u)) >> 16;   // RNE
    return (u16)r;
}
__device__ __forceinline__ float bf2f(u16 v){
    u32 u = ((u32)v) << 16;
    return __builtin_bit_cast(float, u);
}

// async global->LDS, 16B per lane; LDS dest is wave-uniform base + lane*16
__device__ __forceinline__ void gll16(const u16* g, void* lds){
#if HAS_GLL
    __builtin_amdgcn_global_load_lds(
        (const __attribute__((address_space(1))) unsigned int*)g,
        (__attribute__((address_space(3))) unsigned int*)lds, 16, 0, 0);
#endif
}

// counted-vmcnt barrier (m218 pattern)
template<int N> __device__ __forceinline__ void waitbar(){
    if constexpr (N==0) asm volatile("s_waitcnt vmcnt(0) lgkmcnt(0)\ns_barrier" ::: "memory");
    else if constexpr (N==4) asm volatile("s_waitcnt vmcnt(4) lgkmcnt(0)\ns_barrier" ::: "memory");
    else if constexpr (N==8) asm volatile("s_waitcnt vmcnt(8) lgkmcnt(0)\ns_barrier" ::: "memory");
    else asm volatile("s_waitcnt vmcnt(0) lgkmcnt(0)\ns_barrier" ::: "memory");
    __builtin_amdgcn_sched_barrier(0);
}
// release barrier: drain THIS wave's LDS reads, keep vmcnt prefetch in flight.
__device__ __forceinline__ void bar_release(){
    asm volatile("s_waitcnt lgkmcnt(0)\ns_barrier" ::: "memory");
    __builtin_amdgcn_sched_barrier(0);
}

// ---- MFMA wrapper: SFINAE hedge over builtin operand type ----
template<typename V>
__device__ __forceinline__ auto mfma_try(V a, V b, f32x4 c, int)
    -> decltype(__builtin_amdgcn_mfma_f32_16x16x32_bf16(a, b, c, 0, 0, 0))
{ return __builtin_amdgcn_mfma_f32_16x16x32_bf16(a, b, c, 0, 0, 0); }

template<typename V>
__device__ __forceinline__ f32x4 mfma_try(V a, V b, f32x4 c, long)
{
    return __builtin_amdgcn_mfma_f32_16x16x32_bf16(
        __builtin_bit_cast(b16x8, a), __builtin_bit_cast(b16x8, b), c, 0, 0, 0);
}
__device__ __forceinline__ f32x4 mfma_bf16(s16x8 a, s16x8 b, f32x4 c){ return mfma_try(a, b, c, 0); }

// ---------------- LayerNorm f32 out (final only) ----------------
__global__ __launch_bounds__(64) void ln_k(const float* __restrict__ X,
    const float* __restrict__ w, const float* __restrict__ b, float* __restrict__ Y)
{
    int row = blockIdx.x;
    int lane = threadIdx.x;
    const float* x = X + (size_t)row*DD;
    float v[6]; float s=0.f, s2=0.f;
    #pragma unroll
    for (int j=0;j<6;j++){ float t = x[lane + j*64]; v[j]=t; s+=t; s2+=t*t; }
    #pragma unroll
    for (int o=32;o>=1;o>>=1){ s += __shfl_xor(s,o); s2 += __shfl_xor(s2,o); }
    float m = s*(1.f/DD);
    float var = s2*(1.f/DD) - m*m;
    float rstd = rsqrtf(var + 1e-5f);
    #pragma unroll
    for (int j=0;j<6;j++){
        int c = lane + j*64;
        Y[(size_t)row*DD + c] = (v[j]-m)*rstd*w[c] + b[c];
    }
}

// ---------------- Patch gather -> bf16 (B*L, 768) ----------------
__global__ void gather_k(const float* __restrict__ x, u16* __restrict__ P)
{
    int idx = blockIdx.x*blockDim.x + threadIdx.x;
    if (idx >= MROWS*768) return;
    int k = idx % 768;
    int bl = idx / 768;
    int l = bl % LL;
    int b = bl / LL;
    int c = k >> 8;
    int rem = k & 255;
    int dy = rem >> 4, dx = rem & 15;
    int py = l / 14, px = l % 14;
    P[idx] = f2bf(x[(((size_t)b*3 + c)*224 + (py*16+dy))*224 + (px*16+dx)]);
}

// ---------------- MFMA bf16 GEMM (counted-vmcnt 2-buffer pipeline; early C-read) ----------------
__device__ __forceinline__ int swz(int row, int chunk){
    return (row << 7) + ((chunk ^ (row & 7)) << 4);
}

template<int EPI, bool WB, int CFG, int PRO, int K>
__global__ __launch_bounds__(256) void mgemm_k(
    const u16* __restrict__ A, const float* __restrict__ Af,
    const float* __restrict__ lnw, const float* __restrict__ lnb,
    const void* __restrict__ W1v, const void* __restrict__ W2v,
    const float* __restrict__ bias1, const float* __restrict__ bias2,
    float* __restrict__ Cf, u16* __restrict__ Cb,
    int M, int N)
{
    constexpr int  BM   = (CFG==1)?32:16;
    constexpr int  FM   = (CFG==2)?1:2;
    constexpr int  FN   = 2;
    constexpr int  NAR  = (BM+31)/32;
    constexpr bool DUAL = (EPI==4);
    constexpr bool RES  = (EPI==2 || EPI==3);
    constexpr int  ABY  = BM*128;
    constexpr int  BBY  = 128*128;
    constexpr bool ASY  = WB && (HAS_GLL==1);
    constexpr int  NKT  = K >> 6;
    constexpr int  NLW  = DUAL ? 8 : 4;
    __shared__ __attribute__((aligned(16))) char sm[2*ABY + 2*BBY + (DUAL ? 2*BBY : 0)];
    char* A0 = sm;          char* A1 = sm + ABY;
    char* B0 = sm + 2*ABY;  char* B1 = B0 + BBY;
    char* C0 = B1 + BBY;    char* C1 = C0 + BBY;

    const int tid = threadIdx.x;
    const int row0 = blockIdx.y * BM;
    const int col0 = blockIdx.x << 7;
    const int w = tid >> 6, lane = tid & 63;
    const int wn  = w;
    const int lr = lane & 15, lk = lane >> 4;
    const int ar0 = tid >> 3, ac8 = tid & 7;
    const bool apart = (CFG != 2) || (tid < 128);

    const u16*   W1b = (const u16*)W1v;
    const u16*   W2b = (const u16*)W2v;
    const float* W1f = (const float*)W1v;
    const float* W2f = (const float*)W2v;

    f32x4 acc [FM][FN] = {};
    f32x4 acc2[FM][FN] = {};

    float cres[FM][FN][4];
    if (RES){
        #pragma unroll
        for (int n=0;n<FN;n++){
            int gc = col0 + wn*32 + n*16 + lr;
            #pragma unroll
            for (int m=0;m<FM;m++){
                #pragma unroll
                for (int r=0;r<4;r++){
                    int gr = row0 + m*16 + lk*4 + r;
                    cres[m][n][r] = (gc < N && gr < M) ? Cf[(size_t)gr*N + gc] : 0.f;
                }
            }
        }
    }

    s16x8 aval[NAR];
    s16x8 bval[4], b2val[4];
    float4 bvf[8], b2vf[8];
    s16x8 lnr[(PRO==1)?NKT:1];

    if (PRO == 1 && apart){
        const float* xrow = Af + (size_t)(row0 + ar0)*DD;
        float4 va[6], vb[6];
        float s = 0.f, s2 = 0.f;
        #pragma unroll
        for (int j=0;j<6;j++){
            va[j] = *(const float4*)(xrow + j*64 + ac8*8);
            vb[j] = *(const float4*)(xrow + j*64 + ac8*8 + 4);
            s  += va[j].x+va[j].y+va[j].z+va[j].w + vb[j].x+vb[j].y+vb[j].z+vb[j].w;
            s2 += va[j].x*va[j].x+va[j].y*va[j].y+va[j].z*va[j].z+va[j].w*va[j].w
                + vb[j].x*vb[j].x+vb[j].y*vb[j].y+vb[j].z*vb[j].z+vb[j].w*vb[j].w;
        }
        #pragma unroll
        for (int o=1;o<8;o<<=1){ s += __shfl_xor(s,o); s2 += __shfl_xor(s2,o); }
        float m = s*(1.f/DD);
        float rstd = rsqrtf(s2*(1.f/DD) - m*m + 1e-5f);
        #pragma unroll
        for (int j=0;j<6;j++){
            int c0 = j*64 + ac8*8;
            float4 w0 = *(const float4*)(lnw + c0);
            float4 w1 = *(const float4*)(lnw + c0 + 4);
            float4 b0 = *(const float4*)(lnb + c0);
            float4 b1 = *(const float4*)(lnb + c0 + 4);
            s16x8 ov;
            ov[0]=(short)f2bf((va[j].x-m)*rstd*w0.x+b0.x);
            ov[1]=(short)f2bf((va[j].y-m)*rstd*w0.y+b0.y);
            ov[2]=(short)f2bf((va[j].z-m)*rstd*w0.z+b0.z);
            ov[3]=(short)f2bf((va[j].w-m)*rstd*w0.w+b0.w);
            ov[4]=(short)f2bf((vb[j].x-m)*rstd*w1.x+b1.x);
            ov[5]=(short)f2bf((vb[j].y-m)*rstd*w1.y+b1.y);
            ov[6]=(short)f2bf((vb[j].z-m)*rstd*w1.z+b1.z);
            ov[7]=(short)f2bf((vb[j].w-m)*rstd*w1.w+b1.w);
            if (j < NKT) lnr[j] = ov;
        }
    }

    auto stageAsync = [&](int kt, char* bA, char* bB, char* bC){
        const int lhi = lane >> 3, llo = lane & 7;
        const int colel = (kt << 6) + ((llo ^ lhi) << 3);
        if (PRO == 0){
            constexpr int ACH = BM/8;
            #pragma unroll
            for (int ci = w; ci < ACH; ci += 4){
                int gr = row0 + ci*8 + lhi;
                gll16(A + (size_t)gr*K + colel, bA + ci*1024);
            }
        }
        #pragma unroll
        for (int i=0;i<4;i++){
            int ci = w*4 + i;
            int gb = col0 + ci*8 + lhi;
            gll16(W1b + (size_t)gb*K + colel, bB + ci*1024);
        }
        if (DUAL){
            #pragma unroll
            for (int i=0;i<4;i++){
                int ci = w*4 + i;
                int gb = col0 + ci*8 + lhi;
                gll16(W2b + (size_t)gb*K + colel, bC + ci*1024);
            }
        }
    };

    auto loadT = [&](int kt){
        const int kb = kt << 6;
        if (PRO == 0 && apart){
            #pragma unroll
            for (int i=0;i<NAR;i++){
                int gr = row0 + i*32 + ar0;
                if (gr < M) aval[i] = *(const s16x8*)(A + (size_t)gr*K + kb + ac8*8);
                else        aval[i] = s16x8{0,0,0,0,0,0,0,0};
            }
        }
        if (WB){
            #pragma unroll
            for (int i=0;i<4;i++){
                int gb = col0 + i*32 + ar0;
                if (gb < N) bval[i] = *(const s16x8*)(W1b + (size_t)gb*K + kb + ac8*8);
                else        bval[i] = s16x8{0,0,0,0,0,0,0,0};
            }
            if (DUAL){
                #pragma unroll
                for (int i=0;i<4;i++){
                    int gb = col0 + i*32 + ar0;
                    if (gb < N) b2val[i] = *(const s16x8*)(W2b + (size_t)gb*K + kb + ac8*8);
                    else        b2val[i] = s16x8{0,0,0,0,0,0,0,0};
                }
            }
        } else {
            #pragma unroll
            for (int i=0;i<8;i++){
                int ss = i*256 + tid;
                int r = ss >> 4, q = ss & 15;
                int gb = col0 + r;
                if (gb < N) bvf[i] = *(const float4*)(W1f + (size_t)gb*K + kb + q*4);
                else        bvf[i] = float4{0,0,0,0};
            }
            if (DUAL){
                #pragma unroll
                for (int i=0;i<8;i++){
                    int ss = i*256 + tid;
                    int r = ss >> 4, q = ss & 15;
                    int gb = col0 + r;
                    if (gb < N) b2vf[i] = *(const float4*)(W2f + (size_t)gb*K + kb + q*4);
                    else        b2vf[i] = float4{0,0,0,0};
                }
            }
        }
    };
    auto writeT = [&](char* bA, char* bB, char* bC){
        if (PRO == 0 && apart){
            #pragma unroll
            for (int i=0;i<NAR;i++)
                *(s16x8*)(bA + swz(i*32 + ar0, ac8)) = aval[i];
        }
        if (WB){
            #pragma unroll
            for (int i=0;i<4;i++)
                *(s16x8*)(bB + swz(i*32 + ar0, ac8)) = bval[i];
            if (DUAL){
                #pragma unroll
                for (int i=0;i<4;i++)
                    *(s16x8*)(bC + swz(i*32 + ar0, ac8)) = b2val[i];
            }
        } else {
            #pragma unroll
            for (int i=0;i<8;i++){
                int ss = i*256 + tid;
                int r = ss >> 4, q = ss & 15;
                float4 v = bvf[i];
                s16x4 cv = { (short)f2bf(v.x), (short)f2bf(v.y), (short)f2bf(v.z), (short)f2bf(v.w) };
                int off = (r << 7) + (((q >> 1) ^ (r & 7)) << 4) + ((q & 1) << 3);
                *(s16x4*)(bB + off) = cv;
            }
            if (DUAL){
                #pragma unroll
                for (int i=0;i<8;i++){
                    int ss = i*256 + tid;
                    int r = ss >> 4, q = ss & 15;
                    float4 v = b2vf[i];
                    s16x4 cv = { (short)f2bf(v.x), (short)f2bf(v.y), (short)f2bf(v.z), (short)f2bf(v.w) };
                    int off = (r << 7) + (((q >> 1) ^ (r & 7)) << 4) + ((q & 1) << 3);
                    *(s16x4*)(bC + off) = cv;
                }
            }
        }
    };

    auto compute = [&](char* cA, char* cB, char* cC){
        #pragma unroll
        for (int ks=0; ks<2; ks++){
            s16x8 af[FM], bfr[FN];
            #pragma unroll
            for (int m=0;m<FM;m++)
                af[m] = *(const s16x8*)(cA + swz(m*16 + lr, ks*4 + lk));
            #pragma unroll
            for (int n=0;n<FN;n++)
                bfr[n] = *(const s16x8*)(cB + swz(wn*32 + n*16 + lr, ks*4 + lk));
            #pragma unroll
            for (int m=0;m<FM;m++)
                #pragma unroll
                for (int n=0;n<FN;n++)
                    acc[m][n] = mfma_bf16(af[m], bfr[n], acc[m][n]);
            if (DUAL){
                s16x8 b2r[FN];
                #pragma unroll
                for (int n=0;n<FN;n++)
                    b2r[n] = *(const s16x8*)(cC + swz(wn*32 + n*16 + lr, ks*4 + lk));
                #pragma unroll
                for (int m=0;m<FM;m++)
                    #pragma unroll
                    for (int n=0;n<FN;n++)
                        acc2[m][n] = mfma_bf16(af[m], b2r[n], acc2[m][n]);
            }
        }
    };

    if (ASY){
        stageAsync(0, A0, B0, C0);
        if (NKT > 1) stageAsync(1, A1, B1, C1);
        if (PRO == 1 && apart){
            *(s16x8*)(A0 + swz(ar0, ac8)) = lnr[0];
            if (NKT > 1) *(s16x8*)(A1 + swz(ar0, ac8)) = lnr[(1 < NKT) ? 1 : 0];
        }
        if (NKT > 1) waitbar<NLW>(); else waitbar<0>();
        #pragma unroll
        for (int kt=0; kt<NKT; kt++){
            if (kt & 1) compute(A1, B1, C1);
            else        compute(A0, B0, C0);
            if (kt+1 < NKT){
                bar_release();
                if (kt+2 < NKT){
                    char* rA = (kt&1)?A1:A0; char* rB = (kt&1)?B1:B0; char* rC = (kt&1)?C1:C0;
                    stageAsync(kt+2, rA, rB, rC);
                    if (PRO == 1 && apart)
                        *(s16x8*)(rA + swz(ar0, ac8)) = lnr[(kt+2 < NKT) ? (kt+2) : 0];
                    waitbar<NLW>();
                } else {
                    waitbar<0>();
                }
            }
        }
    } else {
        loadT(0); writeT(A0, B0, C0);
        if (PRO == 1 && apart) *(s16x8*)(A0 + swz(ar0, ac8)) = lnr[0];
        __syncthreads();
        #pragma unroll
        for (int kt=0; kt<NKT; kt++){
            const bool more = (kt+1 < NKT);
            char* nA = (kt&1)?A0:A1; char* nB = (kt&1)?B0:B1; char* nC = (kt&1)?C0:C1;
            if (more){
                loadT(kt+1);
                if (PRO == 1 && apart) *(s16x8*)(nA + swz(ar0, ac8)) = lnr[(kt+1 < NKT) ? (kt+1) : 0];
            }
            if (kt & 1) compute(A1, B1, C1);
            else        compute(A0, B0, C0);
            if (more) writeT(nA, nB, nC);
            __syncthreads();
        }
    }

    #pragma unroll
    for (int n=0;n<FN;n++){
        int gc = col0 + wn*32 + n*16 + lr;
        if (gc >= N) continue;
        float b1 = 0.f, b2 = 0.f;
        if (EPI==1||EPI==3||EPI==4) b1 = bias1[gc];
        if (EPI==4) b2 = bias2[gc];
        #pragma unroll
        for (int m=0;m<FM;m++){
            #pragma unroll
            for (int r=0;r<4;r++){
                int gr = row0 + m*16 + lk*4 + r;
                if (gr >= M) continue;
                float v = acc[m][n][r];
                if (EPI==1||EPI==3) v += b1;
                if (RES) v += cres[m][n][r];
                if (EPI==4){
                    float v1 = v + b1;
                    float v2 = acc2[m][n][r] + b2;
                    Cb[(size_t)gr*N + gc] = f2bf(v1 * sigmoidf_(v1) * v2);
                } else if (EPI==6){
                    Cb[(size_t)gr*N + gc] = f2bf(v);
                } else {
                    Cf[(size_t)gr*N + gc] = v;
                }
            }
        }
    }
}

// ---------------- fp32 -> bf16 weight conversion ----------------
__global__ void cvtw_k(const float* __restrict__ s, u16* __restrict__ d, int n)
{
    int i = blockIdx.x*blockDim.x + threadIdx.x;
    int idx = i*4;
    if (idx + 4 <= n){
        float4 v = *(const float4*)(s + idx);
        s16x4 cv = { (short)f2bf(v.x), (short)f2bf(v.y), (short)f2bf(v.z), (short)f2bf(v.w) };
        *(s16x4*)(d + idx) = cv;
    } else {
        for (int j=idx;j<n;j++) d[j] = f2bf(s[j]);
    }
}

// ---------------- out_w transpose: WoT[L][dd][e] = Wo[L][e][dd] (f32) ----------------
__global__ void cvtT_k(const float* __restrict__ s, float* __restrict__ d)
{
    int idx = blockIdx.x*blockDim.x + threadIdx.x;
    if (idx >= NDEPTH*DD*DD) return;
    int e  = idx % DD;
    int dd = (idx / DD) % DD;
    int L  = idx / (DD*DD);
    d[idx] = s[(size_t)L*DD*DD + (size_t)e*DD + dd];
}

// ---------------- Scan phase A (x_proj fused) ----------------
__global__ __launch_bounds__(384) void scanA_k(
    const float* __restrict__ Wx, const u16* __restrict__ xzb,
    const float* __restrict__ cw, const float* __restrict__ cb,
    const float* __restrict__ dtw, const float* __restrict__ dtb,
    const float* __restrict__ a_log,
    float* __restrict__ Pout, float* __restrict__ Sout,
    float2* __restrict__ dtxv, float* __restrict__ dbc)
{
    __shared__ float xaS[CHL][DD+4];
    __shared__ float Ds[CHL][56];
    int b = blockIdx.x / NCH;
    int c = blockIdx.x % NCH;
    int d = threadIdx.x;

    float cwr[4];
    #pragma unroll
    for (int k=0;k<4;k++) cwr[k] = cw[d*4+k];
    float cbv = cb[d];
    int l0 = c*CHL;
    float p3=0.f, p2=0.f, p1=0.f;
    if (l0 >= 3) p3 = bf2f(xzb[(size_t)(b*LL+l0-3)*768 + d]);
    if (l0 >= 2) p2 = bf2f(xzb[(size_t)(b*LL+l0-2)*768 + d]);
    if (l0 >= 1) p1 = bf2f(xzb[(size_t)(b*LL+l0-1)*768 + d]);
    float xv[CHL];
    #pragma unroll
    for (int j=0;j<CHL;j++){
        int row = b*LL + l0 + j;
        float cur = bf2f(xzb[(size_t)row*768 + d]);
        float a = cbv;
        a = fmaf(p3, cwr[0], a); a = fmaf(p2, cwr[1], a);
        a = fmaf(p1, cwr[2], a); a = fmaf(cur, cwr[3], a);
        p3 = p2; p2 = p1; p1 = cur;
        xv[j] = a * sigmoidf_(a);
        xaS[j][d] = xv[j];
    }
    __syncthreads();

    for (int t = d; t < CHL*56; t += 384){
        int q = t / CHL, j = t - q*CHL;
        const float* Wr = Wx + (size_t)q*DD;
        float accd = 0.f;
        #pragma unroll 8
        for (int dd=0; dd<DD; dd+=4){
            float4 wv = *(const float4*)(Wr + dd);
            accd = fmaf(xaS[j][dd],   wv.x, accd);
            accd = fmaf(xaS[j][dd+1], wv.y, accd);
            accd = fmaf(xaS[j][dd+2], wv.z, accd);
            accd = fmaf(xaS[j][dd+3], wv.w, accd);
        }
        Ds[j][q] = accd;
        dbc[(size_t)(b*LL + l0 + j)*56 + q] = accd;
    }
    __syncthreads();

    float dtwr[RRANK];
    #pragma unroll
    for (int r=0;r<RRANK;r++) dtwr[r] = dtw[d*RRANK + r];
    float dtbv = dtb[d];
    float Aa[NST];
    #pragma unroll
    for (int n=0;n<NST;n++) Aa[n] = -__expf(a_log[d*NST+n]);
    float hst[NST], P[NST];
    #pragma unroll
    for (int n=0;n<NST;n++){ hst[n]=0.f; P[n]=1.f; }
    #pragma unroll
    for (int j=0;j<CHL;j++){
        int row = b*LL + l0 + j;
        float t = dtbv;
        #pragma unroll
        for (int r=0;r<RRANK;r++) t = fmaf(dtwr[r], Ds[j][r], t);
        float dtv = (t > 20.f) ? t : log1pf(__expf(t));
        dtxv[(size_t)row*DD + d] = float2{dtv, xv[j]};
        float du = dtv*xv[j];
        #pragma unroll
        for (int n=0;n<NST;n++){
            float e = __expf(dtv*Aa[n]);
            hst[n] = fmaf(hst[n], e, du*Ds[j][24+n]);
            P[n] *= e;
        }
    }
    size_t base = ((size_t)(b*NCH + c)*DD + d)*NST;
    #pragma unroll
    for (int n=0;n<NST;n++){ Pout[base+n]=P[n]; Sout[base+n]=hst[n]; }
}

// ---------------- Scan phase C: prefix + replay + gate; FUSE=1: out_proj GEMV
//  with TRANSPOSED WoT (coalesced) + residual h update; FUSE=0: write bf16 yg ----------------
template<int FUSE>
__global__ __launch_bounds__(384) void scanC_k(
    const float* __restrict__ dbc, const float2* __restrict__ dtxv,
    const u16* __restrict__ xzb, const float* __restrict__ a_log,
    const float* __restrict__ Pin, const float* __restrict__ Sin,
    const float* __restrict__ dskip, const float* __restrict__ WoT,
    float* __restrict__ h, u16* __restrict__ yg)
{
    __shared__ float ygS[CHL][DD+4];
    __shared__ float Ds[CHL][56];
    int b = blockIdx.x / NCH;
    int c = blockIdx.x % NCH;
    int d = threadIdx.x;
    for (int t = threadIdx.x; t < CHL*56; t += 384){
        int j = t/56, q = t%56;
        Ds[j][q] = dbc[(size_t)(b*LL + c*CHL + j)*56 + q];
    }
    __syncthreads();
    float hst[NST];
    #pragma unroll
    for (int n=0;n<NST;n++) hst[n]=0.f;
    for (int cc=0; cc<c; cc++){
        size_t base = ((size_t)(b*NCH + cc)*DD + d)*NST;
        #pragma unroll
        for (int n=0;n<NST;n++)
            hst[n] = fmaf(Pin[base+n], hst[n], Sin[base+n]);
    }
    float Aa[NST];
    #pragma unroll
    for (int n=0;n<NST;n++) Aa[n] = -__expf(a_log[d*NST+n]);
    float dsk = dskip[d];
    int l0 = c*CHL;
    #pragma unroll
    for (int j=0;j<CHL;j++){
        int row = b*LL + l0 + j;
        float2 dx = dtxv[(size_t)row*DD + d];
        float dtv = dx.x, xv = dx.y;
        float du = dtv*xv;
        float y = 0.f;
        #pragma unroll
        for (int n=0;n<NST;n++){
            float e = __expf(dtv*Aa[n]);
            hst[n] = fmaf(hst[n], e, du*Ds[j][24+n]);
            y = fmaf(hst[n], Ds[j][40+n], y);
        }
        float zv = bf2f(xzb[(size_t)row*768 + 384 + d]);
        float g = zv * sigmoidf_(zv);
        float yv = (y + dsk*xv)*g;
        if (FUSE) ygS[j][d] = yv;
        else      yg[(size_t)row*DD + d] = f2bf(yv);
    }
    if (FUSE){
        __syncthreads();
        // out_proj GEMV, coalesced: thread d loads WoT[dd][d] (consecutive lanes ->
        // consecutive addresses); ygS[j][dd] is a same-address LDS broadcast.
        float o[CHL];
        #pragma unroll
        for (int j=0;j<CHL;j++) o[j] = 0.f;
        #pragma unroll 8
        for (int dd=0; dd<DD; dd++){
            float wv = WoT[(size_t)dd*DD + d];
            #pragma unroll
            for (int j=0;j<CHL;j++)
                o[j] = fmaf(ygS[j][dd], wv, o[j]);
        }
        #pragma unroll
        for (int j=0;j<CHL;j++){
            size_t idx = (size_t)(b*LL + l0 + j)*DD + d;
            h[idx] += o[j];
        }
    }
}

// ---------------- host-side MFMA launcher (WB gating) ----------------
template<int EPI, int CFG, int PRO, int K>
static void mg(bool wb, dim3 g, hipStream_t s,
               const void* A, const float* Af, const float* lnw, const float* lnb,
               const void* Wb, const void* Wf, const void* W2b, const void* W2f,
               const float* b1, const float* b2, float* Cf, u16* Cb,
               int M, int N)
{
    if (wb) mgemm_k<EPI,true ,CFG,PRO,K><<<g,256,0,s>>>((const u16*)A, Af, lnw, lnb, Wb, W2b, b1, b2, Cf, Cb, M, N);
    else    mgemm_k<EPI,false,CFG,PRO,K><<<g,256,0,s>>>((const u16*)A, Af, lnw, lnb, Wf, W2f, b1, b2, Cf, Cb, M, N);
}

extern "C" void kernel_launch(void* const* d_in, const int* in_sizes, int n_in,
                              void* d_out, int out_size, void* d_ws, size_t ws_size,
                              hipStream_t stream)
{
    const float* x         = (const float*)d_in[0];
    const float* patch_w   = (const float*)d_in[1];
    const float* patch_b   = (const float*)d_in[2];
    const float* norm1_w   = (const float*)d_in[3];
    const float* norm1_b   = (const float*)d_in[4];
    const float* in_proj_w = (const float*)d_in[5];
    const float* conv_w    = (const float*)d_in[6];
    const float* conv_b    = (const float*)d_in[7];
    const float* x_proj_w  = (const float*)d_in[8];
    const float* dt_w      = (const float*)d_in[9];
    const float* dt_b      = (const float*)d_in[10];
    const float* A_log     = (const float*)d_in[11];
    const float* D_skip    = (const float*)d_in[12];
    const float* out_w     = (const float*)d_in[13];
    const float* norm2_w   = (const float*)d_in[14];
    const float* norm2_b   = (const float*)d_in[15];
    const float* w1_w      = (const float*)d_in[16];
    const float* w1_b      = (const float*)d_in[17];
    const float* w2_w      = (const float*)d_in[18];
    const float* w2_b      = (const float*)d_in[19];
    const float* w3_w      = (const float*)d_in[20];
    const float* w3_b      = (const float*)d_in[21];
    const float* normf_w   = (const float*)d_in[22];
    const float* normf_b   = (const float*)d_in[23];

    char* wsb = (char*)d_ws;
    size_t o = 0;
    auto take = [&](size_t bytes) -> char* {
        char* p = wsb + o;
        o += (bytes + 255) & ~(size_t)255;
        return p;
    };

    float* h    = (float*)take((size_t)602112*4);
    float* dbc  = (float*)take((size_t)87808*4);
    float* Pb   = (float*)take((size_t)BB*NCH*DD*NST*4);
    float* Sb   = (float*)take((size_t)BB*NCH*DD*NST*4);
    float2* dtxv= (float2*)take((size_t)MROWS*DD*8);
    u16*  xzb   = (u16*)take((size_t)1204224*2);
    u16*  yg    = (u16*)take((size_t)602112*2);
    u16*  hid   = (u16*)take((size_t)1605632*2);
    u16*  patches = hid;   // alias: consumed before hid is produced

    const size_t NPW = 294912, NIN = 7077888, NOUT = 3538944,
                 NW1 = 9437184, NW2 = 9437184, NW3 = 9437184;
    u16*   wcP  = (u16*)take(NPW*2);
    u16*   wcI  = (u16*)take(NIN*2);
    u16*   wc1  = (u16*)take(NW1*2);
    u16*   wc2  = (u16*)take(NW2*2);
    u16*   wc3  = (u16*)take(NW3*2);
    float* wcOT = (float*)take(NOUT*4);   // transposed out_w (f32)
    bool wb = (ws_size >= o);

    if (wb){
        cvtw_k<<<(int)((NPW/4+255)/256), 256, 0, stream>>>(patch_w, wcP, (int)NPW);
        cvtw_k<<<(int)((NIN/4+255)/256), 256, 0, stream>>>(in_proj_w, wcI, (int)NIN);
        cvtw_k<<<(int)((NW1/4+255)/256), 256, 0, stream>>>(w1_w, wc1, (int)NW1);
        cvtw_k<<<(int)((NW2/4+255)/256), 256, 0, stream>>>(w2_w, wc2, (int)NW2);
        cvtw_k<<<(int)((NW3/4+255)/256), 256, 0, stream>>>(w3_w, wc3, (int)NW3);
        cvtT_k<<<(int)((NOUT+255)/256), 256, 0, stream>>>(out_w, wcOT);
    }

    const int GY32 = MROWS/32;   // 49
    const int GY16 = MROWS/16;   // 98

    // Patch embedding
    gather_k<<<(MROWS*768+255)/256, 256, 0, stream>>>(x, patches);
    mg<1,2,0,768>(wb, dim3(3,GY16), stream, patches, nullptr, nullptr, nullptr,
              wcP, patch_w, nullptr, nullptr, patch_b, nullptr, h, nullptr, MROWS, DD);

    for (int i=0;i<NDEPTH;i++){
        // in_proj with register-LN prologue -> xzb bf16 (CFG1, 294 blocks)
        mg<6,1,1,384>(wb, dim3(6,GY32), stream, nullptr, h, norm1_w + i*DD, norm1_b + i*DD,
                  wcI + (size_t)i*768*DD, in_proj_w + (size_t)i*768*DD, nullptr, nullptr,
                  nullptr, nullptr, nullptr, xzb, MROWS, 768);
        // fused conv+SiLU + x_proj GEMV + dt + local scan
        scanA_k<<<BB*NCH, 384, 0, stream>>>(x_proj_w + (size_t)i*56*DD, xzb,
                                            conv_w + i*DD*4, conv_b + i*DD,
                                            dt_w + (size_t)i*DD*RRANK, dt_b + i*DD,
                                            A_log + (size_t)i*DD*NST, Pb, Sb, dtxv, dbc);
        if (wb){
            // fused prefix+replay+gate + coalesced out_proj GEMV + residual
            scanC_k<1><<<BB*NCH, 384, 0, stream>>>(dbc, dtxv, xzb, A_log + (size_t)i*DD*NST,
                                                   Pb, Sb, D_skip + i*DD,
                                                   wcOT + (size_t)i*DD*DD, h, nullptr);
        } else {
            scanC_k<0><<<BB*NCH, 384, 0, stream>>>(dbc, dtxv, xzb, A_log + (size_t)i*DD*NST,
                                                   Pb, Sb, D_skip + i*DD,
                                                   nullptr, nullptr, yg);
            mg<2,2,0,384>(false, dim3(3,GY16), stream, yg, nullptr, nullptr, nullptr,
                      nullptr, out_w + (size_t)i*DD*DD, nullptr, nullptr,
                      nullptr, nullptr, h, nullptr, MROWS, DD);
        }
        // MLP dual with register-LN prologue -> hid bf16 (CFG1, 392 blocks)
        mg<4,1,1,384>(wb, dim3(8,GY32), stream, nullptr, h, norm2_w + i*DD, norm2_b + i*DD,
                  wc1 + (size_t)i*HHID*DD, w1_w + (size_t)i*HHID*DD,
                  wc2 + (size_t)i*HHID*DD, w2_w + (size_t)i*HHID*DD,
                  w1_b + i*HHID, w2_b + i*HHID, nullptr, hid, MROWS, HHID);
        mg<3,2,0,1024>(wb, dim3(3,GY16), stream, hid, nullptr, nullptr, nullptr,
                  wc3 + (size_t)i*DD*HHID, w3_w + (size_t)i*DD*HHID, nullptr, nullptr,
                  w3_b + i*DD, nullptr, h, nullptr, MROWS, DD);
    }

    ln_k<<<MROWS, 64, 0, stream>>>(h, normf_w, normf_b, (float*)d_out);
}

// Round 22
// 1961.414 us; speedup vs baseline: 1.3197x; 1.2377x over previous
//
#include <hip/hip_runtime.h>
#include <math.h>

#define BB 8
#define LL 196
#define DD 384
#define NDEPTH 24
#define NST 16
#define RRANK 24
#define HHID 1024
#define MROWS (BB*LL)   /* 1568 */
#define NCH 28
#define CHL 7

typedef float f32x4 __attribute__((ext_vector_type(4)));
typedef short s16x8 __attribute__((ext_vector_type(8)));
typedef short s16x4 __attribute__((ext_vector_type(4)));
typedef __bf16 b16x8 __attribute__((ext_vector_type(8)));
typedef unsigned short u16;
typedef unsigned int u32;

#if defined(__has_builtin)
#  if __has_builtin(__builtin_amdgcn_global_load_lds)
#    define HAS_GLL 1
#  endif
#endif
#ifndef HAS_GLL
#  define HAS_GLL 0
#endif

__device__ __forceinline__ float sigmoidf_(float x){ return 1.f/(1.f+__expf(-x)); }

__device__ __forceinline__ u16 f2bf(float f){
    u32 u = __builtin_bit_cast(u32, f);
    u32 r = (u + 0x7fffu + ((u >> 16) & 1u)) >> 16;   // RNE
    return (u16)r;
}
__device__ __forceinline__ float bf2f(u16 v){
    u32 u = ((u32)v) << 16;
    return __builtin_bit_cast(float, u);
}

// async global->LDS, 16B per lane; LDS dest is wave-uniform base + lane*16
__device__ __forceinline__ void gll16(const u16* g, void* lds){
#if HAS_GLL
    __builtin_amdgcn_global_load_lds(
        (const __attribute__((address_space(1))) unsigned int*)g,
        (__attribute__((address_space(3))) unsigned int*)lds, 16, 0, 0);
#endif
}

// counted-vmcnt barrier (m218 pattern)
template<int N> __device__ __forceinline__ void waitbar(){
    if constexpr (N==0) asm volatile("s_waitcnt vmcnt(0) lgkmcnt(0)\ns_barrier" ::: "memory");
    else if constexpr (N==4) asm volatile("s_waitcnt vmcnt(4) lgkmcnt(0)\ns_barrier" ::: "memory");
    else if constexpr (N==8) asm volatile("s_waitcnt vmcnt(8) lgkmcnt(0)\ns_barrier" ::: "memory");
    else asm volatile("s_waitcnt vmcnt(0) lgkmcnt(0)\ns_barrier" ::: "memory");
    __builtin_amdgcn_sched_barrier(0);
}
// release barrier: drain THIS wave's LDS reads, keep vmcnt prefetch in flight.
__device__ __forceinline__ void bar_release(){
    asm volatile("s_waitcnt lgkmcnt(0)\ns_barrier" ::: "memory");
    __builtin_amdgcn_sched_barrier(0);
}

// ---- MFMA wrapper: SFINAE hedge over builtin operand type ----
template<typename V>
__device__ __forceinline__ auto mfma_try(V a, V b, f32x4 c, int)
    -> decltype(__builtin_amdgcn_mfma_f32_16x16x32_bf16(a, b, c, 0, 0, 0))
{ return __builtin_amdgcn_mfma_f32_16x16x32_bf16(a, b, c, 0, 0, 0); }

template<typename V>
__device__ __forceinline__ f32x4 mfma_try(V a, V b, f32x4 c, long)
{
    return __builtin_amdgcn_mfma_f32_16x16x32_bf16(
        __builtin_bit_cast(b16x8, a), __builtin_bit_cast(b16x8, b), c, 0, 0, 0);
}
__device__ __forceinline__ f32x4 mfma_bf16(s16x8 a, s16x8 b, f32x4 c){ return mfma_try(a, b, c, 0); }

// ---------------- LayerNorm f32 out (final only) ----------------
__global__ __launch_bounds__(64) void ln_k(const float* __restrict__ X,
    const float* __restrict__ w, const float* __restrict__ b, float* __restrict__ Y)
{
    int row = blockIdx.x;
    int lane = threadIdx.x;
    const float* x = X + (size_t)row*DD;
    float v[6]; float s=0.f, s2=0.f;
    #pragma unroll
    for (int j=0;j<6;j++){ float t = x[lane + j*64]; v[j]=t; s+=t; s2+=t*t; }
    #pragma unroll
    for (int o=32;o>=1;o>>=1){ s += __shfl_xor(s,o); s2 += __shfl_xor(s2,o); }
    float m = s*(1.f/DD);
    float var = s2*(1.f/DD) - m*m;
    float rstd = rsqrtf(var + 1e-5f);
    #pragma unroll
    for (int j=0;j<6;j++){
        int c = lane + j*64;
        Y[(size_t)row*DD + c] = (v[j]-m)*rstd*w[c] + b[c];
    }
}

// ---------------- Patch gather -> bf16 (B*L, 768) ----------------
__global__ void gather_k(const float* __restrict__ x, u16* __restrict__ P)
{
    int idx = blockIdx.x*blockDim.x + threadIdx.x;
    if (idx >= MROWS*768) return;
    int k = idx % 768;
    int bl = idx / 768;
    int l = bl % LL;
    int b = bl / LL;
    int c = k >> 8;
    int rem = k & 255;
    int dy = rem >> 4, dx = rem & 15;
    int py = l / 14, px = l % 14;
    P[idx] = f2bf(x[(((size_t)b*3 + c)*224 + (py*16+dy))*224 + (px*16+dx)]);
}

// ---------------- MFMA bf16 GEMM (counted-vmcnt 2-buffer pipeline; early C-read) ----------------
__device__ __forceinline__ int swz(int row, int chunk){
    return (row << 7) + ((chunk ^ (row & 7)) << 4);
}

template<int EPI, bool WB, int CFG, int PRO, int K>
__global__ __launch_bounds__(256) void mgemm_k(
    const u16* __restrict__ A, const float* __restrict__ Af,
    const float* __restrict__ lnw, const float* __restrict__ lnb,
    const void* __restrict__ W1v, const void* __restrict__ W2v,
    const float* __restrict__ bias1, const float* __restrict__ bias2,
    float* __restrict__ Cf, u16* __restrict__ Cb,
    int M, int N)
{
    constexpr int  BM   = (CFG==1)?32:16;
    constexpr int  FM   = (CFG==2)?1:2;
    constexpr int  FN   = 2;
    constexpr int  NAR  = (BM+31)/32;
    constexpr bool DUAL = (EPI==4);
    constexpr bool RES  = (EPI==2 || EPI==3);
    constexpr int  ABY  = BM*128;
    constexpr int  BBY  = 128*128;
    constexpr bool ASY  = WB && (HAS_GLL==1);
    constexpr int  NKT  = K >> 6;
    constexpr int  NLW  = DUAL ? 8 : 4;
    __shared__ __attribute__((aligned(16))) char sm[2*ABY + 2*BBY + (DUAL ? 2*BBY : 0)];
    char* A0 = sm;          char* A1 = sm + ABY;
    char* B0 = sm + 2*ABY;  char* B1 = B0 + BBY;
    char* C0 = B1 + BBY;    char* C1 = C0 + BBY;

    const int tid = threadIdx.x;
    const int row0 = blockIdx.y * BM;
    const int col0 = blockIdx.x << 7;
    const int w = tid >> 6, lane = tid & 63;
    const int wn  = w;
    const int lr = lane & 15, lk = lane >> 4;
    const int ar0 = tid >> 3, ac8 = tid & 7;
    const bool apart = (CFG != 2) || (tid < 128);

    const u16*   W1b = (const u16*)W1v;
    const u16*   W2b = (const u16*)W2v;
    const float* W1f = (const float*)W1v;
    const float* W2f = (const float*)W2v;

    f32x4 acc [FM][FN] = {};
    f32x4 acc2[FM][FN] = {};

    float cres[FM][FN][4];
    if (RES){
        #pragma unroll
        for (int n=0;n<FN;n++){
            int gc = col0 + wn*32 + n*16 + lr;
            #pragma unroll
            for (int m=0;m<FM;m++){
                #pragma unroll
                for (int r=0;r<4;r++){
                    int gr = row0 + m*16 + lk*4 + r;
                    cres[m][n][r] = (gc < N && gr < M) ? Cf[(size_t)gr*N + gc] : 0.f;
                }
            }
        }
    }

    s16x8 aval[NAR];
    s16x8 bval[4], b2val[4];
    float4 bvf[8], b2vf[8];
    s16x8 lnr[(PRO==1)?NKT:1];

    if (PRO == 1 && apart){
        const float* xrow = Af + (size_t)(row0 + ar0)*DD;
        float4 va[6], vb[6];
        float s = 0.f, s2 = 0.f;
        #pragma unroll
        for (int j=0;j<6;j++){
            va[j] = *(const float4*)(xrow + j*64 + ac8*8);
            vb[j] = *(const float4*)(xrow + j*64 + ac8*8 + 4);
            s  += va[j].x+va[j].y+va[j].z+va[j].w + vb[j].x+vb[j].y+vb[j].z+vb[j].w;
            s2 += va[j].x*va[j].x+va[j].y*va[j].y+va[j].z*va[j].z+va[j].w*va[j].w
                + vb[j].x*vb[j].x+vb[j].y*vb[j].y+vb[j].z*vb[j].z+vb[j].w*vb[j].w;
        }
        #pragma unroll
        for (int o=1;o<8;o<<=1){ s += __shfl_xor(s,o); s2 += __shfl_xor(s2,o); }
        float m = s*(1.f/DD);
        float rstd = rsqrtf(s2*(1.f/DD) - m*m + 1e-5f);
        #pragma unroll
        for (int j=0;j<6;j++){
            int c0 = j*64 + ac8*8;
            float4 w0 = *(const float4*)(lnw + c0);
            float4 w1 = *(const float4*)(lnw + c0 + 4);
            float4 b0 = *(const float4*)(lnb + c0);
            float4 b1 = *(const float4*)(lnb + c0 + 4);
            s16x8 ov;
            ov[0]=(short)f2bf((va[j].x-m)*rstd*w0.x+b0.x);
            ov[1]=(short)f2bf((va[j].y-m)*rstd*w0.y+b0.y);
            ov[2]=(short)f2bf((va[j].z-m)*rstd*w0.z+b0.z);
            ov[3]=(short)f2bf((va[j].w-m)*rstd*w0.w+b0.w);
            ov[4]=(short)f2bf((vb[j].x-m)*rstd*w1.x+b1.x);
            ov[5]=(short)f2bf((vb[j].y-m)*rstd*w1.y+b1.y);
            ov[6]=(short)f2bf((vb[j].z-m)*rstd*w1.z+b1.z);
            ov[7]=(short)f2bf((vb[j].w-m)*rstd*w1.w+b1.w);
            if (j < NKT) lnr[j] = ov;
        }
    }

    auto stageAsync = [&](int kt, char* bA, char* bB, char* bC){
        const int lhi = lane >> 3, llo = lane & 7;
        const int colel = (kt << 6) + ((llo ^ lhi) << 3);
        if (PRO == 0){
            constexpr int ACH = BM/8;
            #pragma unroll
            for (int ci = w; ci < ACH; ci += 4){
                int gr = row0 + ci*8 + lhi;
                gll16(A + (size_t)gr*K + colel, bA + ci*1024);
            }
        }
        #pragma unroll
        for (int i=0;i<4;i++){
            int ci = w*4 + i;
            int gb = col0 + ci*8 + lhi;
            gll16(W1b + (size_t)gb*K + colel, bB + ci*1024);
        }
        if (DUAL){
            #pragma unroll
            for (int i=0;i<4;i++){
                int ci = w*4 + i;
                int gb = col0 + ci*8 + lhi;
                gll16(W2b + (size_t)gb*K + colel, bC + ci*1024);
            }
        }
    };

    auto loadT = [&](int kt){
        const int kb = kt << 6;
        if (PRO == 0 && apart){
            #pragma unroll
            for (int i=0;i<NAR;i++){
                int gr = row0 + i*32 + ar0;
                if (gr < M) aval[i] = *(const s16x8*)(A + (size_t)gr*K + kb + ac8*8);
                else        aval[i] = s16x8{0,0,0,0,0,0,0,0};
            }
        }
        if (WB){
            #pragma unroll
            for (int i=0;i<4;i++){
                int gb = col0 + i*32 + ar0;
                if (gb < N) bval[i] = *(const s16x8*)(W1b + (size_t)gb*K + kb + ac8*8);
                else        bval[i] = s16x8{0,0,0,0,0,0,0,0};
            }
            if (DUAL){
                #pragma unroll
                for (int i=0;i<4;i++){
                    int gb = col0 + i*32 + ar0;
                    if (gb < N) b2val[i] = *(const s16x8*)(W2b + (size_t)gb*K + kb + ac8*8);
                    else        b2val[i] = s16x8{0,0,0,0,0,0,0,0};
                }
            }
        } else {
            #pragma unroll
            for (int i=0;i<8;i++){
                int ss = i*256 + tid;
                int r = ss >> 4, q = ss & 15;
                int gb = col0 + r;
                if (gb < N) bvf[i] = *(const float4*)(W1f + (size_t)gb*K + kb + q*4);
                else        bvf[i] = float4{0,0,0,0};
            }
            if (DUAL){
                #pragma unroll
                for (int i=0;i<8;i++){
                    int ss = i*256 + tid;
                    int r = ss >> 4, q = ss & 15;
                    int gb = col0 + r;
                    if (gb < N) b2vf[i] = *(const float4*)(W2f + (size_t)gb*K + kb + q*4);
                    else        b2vf[i] = float4{0,0,0,0};
                }
            }
        }
    };
    auto writeT = [&](char* bA, char* bB, char* bC){
        if (PRO == 0 && apart){
            #pragma unroll
            for (int i=0;i<NAR;i++)
                *(s16x8*)(bA + swz(i*32 + ar0, ac8)) = aval[i];
        }
        if (WB){
            #pragma unroll
            for (int i=0;i<4;i++)
                *(s16x8*)(bB + swz(i*32 + ar0, ac8)) = bval[i];
            if (DUAL){
                #pragma unroll
                for (int i=0;i<4;i++)
                    *(s16x8*)(bC + swz(i*32 + ar0, ac8)) = b2val[i];
            }
        } else {
            #pragma unroll
            for (int i=0;i<8;i++){
                int ss = i*256 + tid;
                int r = ss >> 4, q = ss & 15;
                float4 v = bvf[i];
                s16x4 cv = { (short)f2bf(v.x), (short)f2bf(v.y), (short)f2bf(v.z), (short)f2bf(v.w) };
                int off = (r << 7) + (((q >> 1) ^ (r & 7)) << 4) + ((q & 1) << 3);
                *(s16x4*)(bB + off) = cv;
            }
            if (DUAL){
                #pragma unroll
                for (int i=0;i<8;i++){
                    int ss = i*256 + tid;
                    int r = ss >> 4, q = ss & 15;
                    float4 v = b2vf[i];
                    s16x4 cv = { (short)f2bf(v.x), (short)f2bf(v.y), (short)f2bf(v.z), (short)f2bf(v.w) };
                    int off = (r << 7) + (((q >> 1) ^ (r & 7)) << 4) + ((q & 1) << 3);
                    *(s16x4*)(bC + off) = cv;
                }
            }
        }
    };

    auto compute = [&](char* cA, char* cB, char* cC){
        #pragma unroll
        for (int ks=0; ks<2; ks++){
            s16x8 af[FM], bfr[FN];
            #pragma unroll
            for (int m=0;m<FM;m++)
                af[m] = *(const s16x8*)(cA + swz(m*16 + lr, ks*4 + lk));
            #pragma unroll
            for (int n=0;n<FN;n++)
                bfr[n] = *(const s16x8*)(cB + swz(wn*32 + n*16 + lr, ks*4 + lk));
            #pragma unroll
            for (int m=0;m<FM;m++)
                #pragma unroll
                for (int n=0;n<FN;n++)
                    acc[m][n] = mfma_bf16(af[m], bfr[n], acc[m][n]);
            if (DUAL){
                s16x8 b2r[FN];
                #pragma unroll
                for (int n=0;n<FN;n++)
                    b2r[n] = *(const s16x8*)(cC + swz(wn*32 + n*16 + lr, ks*4 + lk));
                #pragma unroll
                for (int m=0;m<FM;m++)
                    #pragma unroll
                    for (int n=0;n<FN;n++)
                        acc2[m][n] = mfma_bf16(af[m], b2r[n], acc2[m][n]);
            }
        }
    };

    if (ASY){
        stageAsync(0, A0, B0, C0);
        if (NKT > 1) stageAsync(1, A1, B1, C1);
        if (PRO == 1 && apart){
            *(s16x8*)(A0 + swz(ar0, ac8)) = lnr[0];
            if (NKT > 1) *(s16x8*)(A1 + swz(ar0, ac8)) = lnr[(1 < NKT) ? 1 : 0];
        }
        if (NKT > 1) waitbar<NLW>(); else waitbar<0>();
        #pragma unroll
        for (int kt=0; kt<NKT; kt++){
            if (kt & 1) compute(A1, B1, C1);
            else        compute(A0, B0, C0);
            if (kt+1 < NKT){
                bar_release();
                if (kt+2 < NKT){
                    char* rA = (kt&1)?A1:A0; char* rB = (kt&1)?B1:B0; char* rC = (kt&1)?C1:C0;
                    stageAsync(kt+2, rA, rB, rC);
                    if (PRO == 1 && apart)
                        *(s16x8*)(rA + swz(ar0, ac8)) = lnr[(kt+2 < NKT) ? (kt+2) : 0];
                    waitbar<NLW>();
                } else {
                    waitbar<0>();
                }
            }
        }
    } else {
        loadT(0); writeT(A0, B0, C0);
        if (PRO == 1 && apart) *(s16x8*)(A0 + swz(ar0, ac8)) = lnr[0];
        __syncthreads();
        #pragma unroll
        for (int kt=0; kt<NKT; kt++){
            const bool more = (kt+1 < NKT);
            char* nA = (kt&1)?A0:A1; char* nB = (kt&1)?B0:B1; char* nC = (kt&1)?C0:C1;
            if (more){
                loadT(kt+1);
                if (PRO == 1 && apart) *(s16x8*)(nA + swz(ar0, ac8)) = lnr[(kt+1 < NKT) ? (kt+1) : 0];
            }
            if (kt & 1) compute(A1, B1, C1);
            else        compute(A0, B0, C0);
            if (more) writeT(nA, nB, nC);
            __syncthreads();
        }
    }

    #pragma unroll
    for (int n=0;n<FN;n++){
        int gc = col0 + wn*32 + n*16 + lr;
        if (gc >= N) continue;
        float b1 = 0.f, b2 = 0.f;
        if (EPI==1||EPI==3||EPI==4) b1 = bias1[gc];
        if (EPI==4) b2 = bias2[gc];
        #pragma unroll
        for (int m=0;m<FM;m++){
            #pragma unroll
            for (int r=0;r<4;r++){
                int gr = row0 + m*16 + lk*4 + r;
                if (gr >= M) continue;
                float v = acc[m][n][r];
                if (EPI==1||EPI==3) v += b1;
                if (RES) v += cres[m][n][r];
                if (EPI==4){
                    float v1 = v + b1;
                    float v2 = acc2[m][n][r] + b2;
                    Cb[(size_t)gr*N + gc] = f2bf(v1 * sigmoidf_(v1) * v2);
                } else if (EPI==6){
                    Cb[(size_t)gr*N + gc] = f2bf(v);
                } else {
                    Cf[(size_t)gr*N + gc] = v;
                }
            }
        }
    }
}

// ---------------- fp32 -> bf16 weight conversion ----------------
__global__ void cvtw_k(const float* __restrict__ s, u16* __restrict__ d, int n)
{
    int i = blockIdx.x*blockDim.x + threadIdx.x;
    int idx = i*4;
    if (idx + 4 <= n){
        float4 v = *(const float4*)(s + idx);
        s16x4 cv = { (short)f2bf(v.x), (short)f2bf(v.y), (short)f2bf(v.z), (short)f2bf(v.w) };
        *(s16x4*)(d + idx) = cv;
    } else {
        for (int j=idx;j<n;j++) d[j] = f2bf(s[j]);
    }
}

// ---------------- Scan phase A (x_proj fused) ----------------
__global__ __launch_bounds__(384) void scanA_k(
    const float* __restrict__ Wx, const u16* __restrict__ xzb,
    const float* __restrict__ cw, const float* __restrict__ cb,
    const float* __restrict__ dtw, const float* __restrict__ dtb,
    const float* __restrict__ a_log,
    float* __restrict__ Pout, float* __restrict__ Sout,
    float2* __restrict__ dtxv, float* __restrict__ dbc)
{
    __shared__ float xaS[CHL][DD+4];
    __shared__ float Ds[CHL][56];
    int b = blockIdx.x / NCH;
    int c = blockIdx.x % NCH;
    int d = threadIdx.x;

    float cwr[4];
    #pragma unroll
    for (int k=0;k<4;k++) cwr[k] = cw[d*4+k];
    float cbv = cb[d];
    int l0 = c*CHL;
    float p3=0.f, p2=0.f, p1=0.f;
    if (l0 >= 3) p3 = bf2f(xzb[(size_t)(b*LL+l0-3)*768 + d]);
    if (l0 >= 2) p2 = bf2f(xzb[(size_t)(b*LL+l0-2)*768 + d]);
    if (l0 >= 1) p1 = bf2f(xzb[(size_t)(b*LL+l0-1)*768 + d]);
    float xv[CHL];
    #pragma unroll
    for (int j=0;j<CHL;j++){
        int row = b*LL + l0 + j;
        float cur = bf2f(xzb[(size_t)row*768 + d]);
        float a = cbv;
        a = fmaf(p3, cwr[0], a); a = fmaf(p2, cwr[1], a);
        a = fmaf(p1, cwr[2], a); a = fmaf(cur, cwr[3], a);
        p3 = p2; p2 = p1; p1 = cur;
        xv[j] = a * sigmoidf_(a);
        xaS[j][d] = xv[j];
    }
    __syncthreads();

    for (int t = d; t < CHL*56; t += 384){
        int q = t / CHL, j = t - q*CHL;
        const float* Wr = Wx + (size_t)q*DD;
        float accd = 0.f;
        #pragma unroll 8
        for (int dd=0; dd<DD; dd+=4){
            float4 wv = *(const float4*)(Wr + dd);
            accd = fmaf(xaS[j][dd],   wv.x, accd);
            accd = fmaf(xaS[j][dd+1], wv.y, accd);
            accd = fmaf(xaS[j][dd+2], wv.z, accd);
            accd = fmaf(xaS[j][dd+3], wv.w, accd);
        }
        Ds[j][q] = accd;
        dbc[(size_t)(b*LL + l0 + j)*56 + q] = accd;
    }
    __syncthreads();

    float dtwr[RRANK];
    #pragma unroll
    for (int r=0;r<RRANK;r++) dtwr[r] = dtw[d*RRANK + r];
    float dtbv = dtb[d];
    float Aa[NST];
    #pragma unroll
    for (int n=0;n<NST;n++) Aa[n] = -__expf(a_log[d*NST+n]);
    float hst[NST], P[NST];
    #pragma unroll
    for (int n=0;n<NST;n++){ hst[n]=0.f; P[n]=1.f; }
    #pragma unroll
    for (int j=0;j<CHL;j++){
        int row = b*LL + l0 + j;
        float t = dtbv;
        #pragma unroll
        for (int r=0;r<RRANK;r++) t = fmaf(dtwr[r], Ds[j][r], t);
        float dtv = (t > 20.f) ? t : log1pf(__expf(t));
        dtxv[(size_t)row*DD + d] = float2{dtv, xv[j]};
        float du = dtv*xv[j];
        #pragma unroll
        for (int n=0;n<NST;n++){
            float e = __expf(dtv*Aa[n]);
            hst[n] = fmaf(hst[n], e, du*Ds[j][24+n]);
            P[n] *= e;
        }
    }
    size_t base = ((size_t)(b*NCH + c)*DD + d)*NST;
    #pragma unroll
    for (int n=0;n<NST;n++){ Pout[base+n]=P[n]; Sout[base+n]=hst[n]; }
}

// ---------------- Scan phase B (wide): Hin[b][c][d][n] = prefix state before chunk c ----------------
// 49152 threads over (b,d,n), n fastest -> fully coalesced; 28-step serial per thread.
__global__ __launch_bounds__(256) void scanB_k(
    const float* __restrict__ P, const float* __restrict__ S,
    float* __restrict__ Hin)
{
    int t = blockIdx.x*blockDim.x + threadIdx.x;
    if (t >= BB*DD*NST) return;
    int n = t % NST;
    int d = (t / NST) % DD;
    int b = t / (NST*DD);
    float h = 0.f;
    for (int c=0; c<NCH; c++){
        size_t idx = ((size_t)(b*NCH + c)*DD + d)*NST + n;
        Hin[idx] = h;
        h = fmaf(P[idx], h, S[idx]);
    }
}

// ---------------- Scan phase C: Hin + replay from stored {dtv,xv} + gate -> bf16 yg ----------------
__global__ __launch_bounds__(384) void scanC_k(
    const float* __restrict__ dbc, const float2* __restrict__ dtxv,
    const u16* __restrict__ xzb, const float* __restrict__ a_log,
    const float* __restrict__ Hin,
    const float* __restrict__ dskip,
    u16* __restrict__ yg)
{
    int b = blockIdx.x / NCH;
    int c = blockIdx.x % NCH;
    int d = threadIdx.x;
    __shared__ float Ds[CHL][56];
    for (int t = threadIdx.x; t < CHL*56; t += 384){
        int j = t/56, q = t%56;
        Ds[j][q] = dbc[(size_t)(b*LL + c*CHL + j)*56 + q];
    }
    __syncthreads();
    float hst[NST];
    size_t hb = ((size_t)(b*NCH + c)*DD + d)*NST;
    #pragma unroll
    for (int n=0;n<NST;n++) hst[n] = Hin[hb+n];
    float Aa[NST];
    #pragma unroll
    for (int n=0;n<NST;n++) Aa[n] = -__expf(a_log[d*NST+n]);
    float dsk = dskip[d];
    int l0 = c*CHL;
    #pragma unroll
    for (int j=0;j<CHL;j++){
        int row = b*LL + l0 + j;
        float2 dx = dtxv[(size_t)row*DD + d];
        float dtv = dx.x, xv = dx.y;
        float du = dtv*xv;
        float y = 0.f;
        #pragma unroll
        for (int n=0;n<NST;n++){
            float e = __expf(dtv*Aa[n]);
            hst[n] = fmaf(hst[n], e, du*Ds[j][24+n]);
            y = fmaf(hst[n], Ds[j][40+n], y);
        }
        float zv = bf2f(xzb[(size_t)row*768 + 384 + d]);
        float g = zv * sigmoidf_(zv);
        yg[(size_t)row*DD + d] = f2bf((y + dsk*xv)*g);
    }
}

// ---------------- host-side MFMA launcher (WB gating) ----------------
template<int EPI, int CFG, int PRO, int K>
static void mg(bool wb, dim3 g, hipStream_t s,
               const void* A, const float* Af, const float* lnw, const float* lnb,
               const void* Wb, const void* Wf, const void* W2b, const void* W2f,
               const float* b1, const float* b2, float* Cf, u16* Cb,
               int M, int N)
{
    if (wb) mgemm_k<EPI,true ,CFG,PRO,K><<<g,256,0,s>>>((const u16*)A, Af, lnw, lnb, Wb, W2b, b1, b2, Cf, Cb, M, N);
    else    mgemm_k<EPI,false,CFG,PRO,K><<<g,256,0,s>>>((const u16*)A, Af, lnw, lnb, Wf, W2f, b1, b2, Cf, Cb, M, N);
}

extern "C" void kernel_launch(void* const* d_in, const int* in_sizes, int n_in,
                              void* d_out, int out_size, void* d_ws, size_t ws_size,
                              hipStream_t stream)
{
    const float* x         = (const float*)d_in[0];
    const float* patch_w   = (const float*)d_in[1];
    const float* patch_b   = (const float*)d_in[2];
    const float* norm1_w   = (const float*)d_in[3];
    const float* norm1_b   = (const float*)d_in[4];
    const float* in_proj_w = (const float*)d_in[5];
    const float* conv_w    = (const float*)d_in[6];
    const float* conv_b    = (const float*)d_in[7];
    const float* x_proj_w  = (const float*)d_in[8];
    const float* dt_w      = (const float*)d_in[9];
    const float* dt_b      = (const float*)d_in[10];
    const float* A_log     = (const float*)d_in[11];
    const float* D_skip    = (const float*)d_in[12];
    const float* out_w     = (const float*)d_in[13];
    const float* norm2_w   = (const float*)d_in[14];
    const float* norm2_b   = (const float*)d_in[15];
    const float* w1_w      = (const float*)d_in[16];
    const float* w1_b      = (const float*)d_in[17];
    const float* w2_w      = (const float*)d_in[18];
    const float* w2_b      = (const float*)d_in[19];
    const float* w3_w      = (const float*)d_in[20];
    const float* w3_b      = (const float*)d_in[21];
    const float* normf_w   = (const float*)d_in[22];
    const float* normf_b   = (const float*)d_in[23];

    char* wsb = (char*)d_ws;
    size_t o = 0;
    auto take = [&](size_t bytes) -> char* {
        char* p = wsb + o;
        o += (bytes + 255) & ~(size_t)255;
        return p;
    };

    float* h    = (float*)take((size_t)602112*4);
    float* dbc  = (float*)take((size_t)87808*4);
    float* Pb   = (float*)take((size_t)BB*NCH*DD*NST*4);
    float* Sb   = (float*)take((size_t)BB*NCH*DD*NST*4);
    float* Hi   = (float*)take((size_t)BB*NCH*DD*NST*4);
    float2* dtxv= (float2*)take((size_t)MROWS*DD*8);
    u16*  xzb   = (u16*)take((size_t)1204224*2);
    u16*  yg    = (u16*)take((size_t)602112*2);
    u16*  hid   = (u16*)take((size_t)1605632*2);
    u16*  patches = hid;   // alias: consumed before hid is produced

    const size_t NPW = 294912, NIN = 7077888, NOUT = 3538944,
                 NW1 = 9437184, NW2 = 9437184, NW3 = 9437184;
    u16* wcP = (u16*)take(NPW*2);
    u16* wcI = (u16*)take(NIN*2);
    u16* wcO = (u16*)take(NOUT*2);
    u16* wc1 = (u16*)take(NW1*2);
    u16* wc2 = (u16*)take(NW2*2);
    u16* wc3 = (u16*)take(NW3*2);
    bool wb = (ws_size >= o);

    if (wb){
        cvtw_k<<<(int)((NPW/4+255)/256), 256, 0, stream>>>(patch_w, wcP, (int)NPW);
        cvtw_k<<<(int)((NIN/4+255)/256), 256, 0, stream>>>(in_proj_w, wcI, (int)NIN);
        cvtw_k<<<(int)((NOUT/4+255)/256),256, 0, stream>>>(out_w, wcO, (int)NOUT);
        cvtw_k<<<(int)((NW1/4+255)/256), 256, 0, stream>>>(w1_w, wc1, (int)NW1);
        cvtw_k<<<(int)((NW2/4+255)/256), 256, 0, stream>>>(w2_w, wc2, (int)NW2);
        cvtw_k<<<(int)((NW3/4+255)/256), 256, 0, stream>>>(w3_w, wc3, (int)NW3);
    }

    const int GY32 = MROWS/32;   // 49
    const int GY16 = MROWS/16;   // 98

    // Patch embedding
    gather_k<<<(MROWS*768+255)/256, 256, 0, stream>>>(x, patches);
    mg<1,2,0,768>(wb, dim3(3,GY16), stream, patches, nullptr, nullptr, nullptr,
              wcP, patch_w, nullptr, nullptr, patch_b, nullptr, h, nullptr, MROWS, DD);

    for (int i=0;i<NDEPTH;i++){
        // in_proj with register-LN prologue -> xzb bf16 (CFG1, 294 blocks)
        mg<6,1,1,384>(wb, dim3(6,GY32), stream, nullptr, h, norm1_w + i*DD, norm1_b + i*DD,
                  wcI + (size_t)i*768*DD, in_proj_w + (size_t)i*768*DD, nullptr, nullptr,
                  nullptr, nullptr, nullptr, xzb, MROWS, 768);
        // fused conv+SiLU + x_proj GEMV + dt + local scan
        scanA_k<<<BB*NCH, 384, 0, stream>>>(x_proj_w + (size_t)i*56*DD, xzb,
                                            conv_w + i*DD*4, conv_b + i*DD,
                                            dt_w + (size_t)i*DD*RRANK, dt_b + i*DD,
                                            A_log + (size_t)i*DD*NST, Pb, Sb, dtxv, dbc);
        // wide chunk-prefix pass: one linear read of P/S
        scanB_k<<<(BB*DD*NST+255)/256, 256, 0, stream>>>(Pb, Sb, Hi);
        // replay from Hin
        scanC_k<<<BB*NCH, 384, 0, stream>>>(dbc, dtxv, xzb, A_log + (size_t)i*DD*NST,
                                            Hi, D_skip + i*DD, yg);
        mg<2,2,0,384>(wb, dim3(3,GY16), stream, yg, nullptr, nullptr, nullptr,
                  wcO + (size_t)i*DD*DD, out_w + (size_t)i*DD*DD, nullptr, nullptr,
                  nullptr, nullptr, h, nullptr, MROWS, DD);
        // MLP dual with register-LN prologue -> hid bf16 (CFG1, 392 blocks)
        mg<4,1,1,384>(wb, dim3(8,GY32), stream, nullptr, h, norm2_w + i*DD, norm2_b + i*DD,
                  wc1 + (size_t)i*HHID*DD, w1_w + (size_t)i*HHID*DD,
                  wc2 + (size_t)i*HHID*DD, w2_w + (size_t)i*HHID*DD,
                  w1_b + i*HHID, w2_b + i*HHID, nullptr, hid, MROWS, HHID);
        mg<3,2,0,1024>(wb, dim3(3,GY16), stream, hid, nullptr, nullptr, nullptr,
                  wc3 + (size_t)i*DD*HHID, w3_w + (size_t)i*DD*HHID, nullptr, nullptr,
                  w3_b + i*DD, nullptr, h, nullptr, MROWS, DD);
    }

    ln_k<<<MROWS, 64, 0, stream>>>(h, normf_w, normf_b, (float*)d_out);
}